// Round 7
// baseline (694.666 us; speedup 1.0000x reference)
//
#include <hip/hip_runtime.h>
#include <hip/hip_cooperative_groups.h>
#include <math.h>

namespace cg = cooperative_groups;

#define EPSBN 1e-5f
#define AADD(p, v) __hip_atomic_fetch_add((p), (v), __ATOMIC_RELAXED, __HIP_MEMORY_SCOPE_AGENT)

typedef unsigned short u16;
typedef short bf16x8 __attribute__((ext_vector_type(8)));
typedef float f32x4 __attribute__((ext_vector_type(4)));
typedef float f32x16 __attribute__((ext_vector_type(16)));
typedef int i32x4 __attribute__((ext_vector_type(4)));

constexpr int NROWS = 8192;
constexpr int NCLS = 10;
constexpr int MPAD = 8832;        // 138 tiles of 64
constexpr int NT_PAD = 138;
constexpr int GY = 8;
constexpr float SCL  = 2.0813689810056077f;   // (log2 e)^2
constexpr float SCL2 = -4.1627379620112154f;  // -2*(log2 e)^2

// ---------- mega workspace offsets (floats) ----------
constexpr size_t MG_W0P = 0;                       // u16[65536]
constexpr size_t MG_H1H = 32768;                   // u16[16384*128]
constexpr size_t MG_H1L = MG_H1H + 1048576;
constexpr size_t MG_SUM = MG_H1L + 1048576;        // 768 floats
constexpr size_t MG_H2  = MG_SUM + 768;            // 16384*64 floats
constexpr size_t MG_PIDX = MG_H2 + 1048576;        // int[8832]
constexpr size_t MG_TCLS = MG_PIDX + MPAD;         // int[144]
constexpr size_t MG_QH  = MG_H1H;                  // overlays (h1 dead after P2)
constexpr size_t MG_QL  = MG_QH + 262144;
constexpr size_t MG_QN2 = MG_QL + 262144;
constexpr size_t MG_KH  = MG_QN2 + NROWS;
constexpr size_t MG_KL  = MG_KH + 282624;
constexpr size_t MG_KN2 = MG_KL + 282624;
constexpr size_t MG_PART = MG_H2;                  // part over h2 (dead after P3)

// ---------- fallback (R5) workspace offsets ----------
constexpr size_t FB_W0P = 0;
constexpr size_t FB_H1H = 32768;
constexpr size_t FB_H1L = FB_H1H + 1048576;
constexpr size_t FB_SUM = FB_H1L + 1048576;
constexpr size_t FB_W1P = FB_SUM + 768;
constexpr size_t FB_B1E = FB_W1P + 16384;
constexpr size_t FB_H2  = FB_B1E + 128;
constexpr size_t FB_PIDX = FB_H2 + 1048576;
constexpr size_t FB_TCLS = FB_PIDX + MPAD;
constexpr size_t FB_QH  = FB_H1H;
constexpr size_t FB_QL  = FB_QH + 262144;
constexpr size_t FB_QN2 = FB_QL + 262144;
constexpr size_t FB_KH  = FB_QN2 + NROWS;
constexpr size_t FB_KL  = FB_KH + 282624;
constexpr size_t FB_KN2 = FB_KL + 282624;
constexpr size_t FB_PART = FB_H2;

__device__ inline u16 f2bf(float f) {
  unsigned u = __float_as_uint(f);
  unsigned r = (u + 0x7fffu + ((u >> 16) & 1u)) >> 16;
  return (u16)r;
}
__device__ inline float bf2f(u16 h) { return __uint_as_float(((unsigned)h) << 16); }

__device__ inline float tanh_fast(float x) {
  float e = __builtin_amdgcn_exp2f(x * 2.88539008f);
  return 1.f - 2.f * __builtin_amdgcn_rcpf(e + 1.f);
}

__device__ inline void glds16(const u16* g, u16* l) {
  __builtin_amdgcn_global_load_lds(
      (const __attribute__((address_space(1))) unsigned int*)g,
      (__attribute__((address_space(3))) unsigned int*)l, 16, 0, 0);
}

// ============================================================================
// MEGA cooperative kernel
// ============================================================================
__global__ __launch_bounds__(256, 4) void k_mega(
    const float* __restrict__ x, const float* __restrict__ xn, const int* __restrict__ yn,
    const float* __restrict__ W0, const float* __restrict__ b0,
    const float* __restrict__ g0, const float* __restrict__ bt0,
    const float* __restrict__ W1, const float* __restrict__ b1,
    const float* __restrict__ g1, const float* __restrict__ bt1,
    float* __restrict__ ws, float* __restrict__ out)
{
  __shared__ __align__(16) char SMEM[38400];
  cg::grid_group grid = cg::this_grid();

  u16*   w0p  = (u16*)(ws + MG_W0P);
  u16*   h1h  = (u16*)(ws + MG_H1H);
  u16*   h1l  = (u16*)(ws + MG_H1L);
  float* sums = ws + MG_SUM;
  float* h2   = ws + MG_H2;
  int*   pidx = (int*)(ws + MG_PIDX);
  int*   tcls = (int*)(ws + MG_TCLS);
  u16*   qh   = (u16*)(ws + MG_QH);
  u16*   ql   = (u16*)(ws + MG_QL);
  float* qn2  = ws + MG_QN2;
  u16*   kh   = (u16*)(ws + MG_KH);
  u16*   kl   = (u16*)(ws + MG_KL);
  float* kn2  = ws + MG_KN2;
  float* part = ws + MG_PART;

  const int tid = threadIdx.x;
  const int nbl = gridDim.x;
  const int w = tid >> 6, l = tid & 63;
  const int l15 = l & 15, l4 = l >> 4;

  // ================= P0: pack W0 | sort | zero sums =================
  for (int job = blockIdx.x; job < 130; job += nbl) {
    if (job < 128) {
      int idx = job * 256 + tid;
      int t = idx & 255, j = idx >> 8;
      float v = W0[idx];
      u16 hi = f2bf(v);
      u16 lo = f2bf(v - bf2f(hi));
      w0p[(t >> 3) * 1024 + j * 8 + (t & 7)] = hi;
      w0p[32768 + (t >> 3) * 1024 + j * 8 + (t & 7)] = lo;
    } else if (job == 129) {
      sums[tid] = 0.f; sums[tid + 256] = 0.f; sums[tid + 512] = 0.f;
    } else {
      int (*cnt)[NCLS] = (int(*)[NCLS])SMEM;
      int (*wtot)[NCLS] = (int(*)[NCLS])(SMEM + 10240);
      int* pstart = (int*)(SMEM + 10400);
      const int lane = l, wv = w;
      __syncthreads();
      #pragma unroll
      for (int c = 0; c < NCLS; ++c) cnt[tid][c] = 0;
      for (int i = tid; i < MPAD; i += 256) pidx[i] = -1;
      for (int i = tid; i < NROWS; i += 256) cnt[tid][yn[i]]++;
      __syncthreads();
      #pragma unroll
      for (int c = 0; c < NCLS; ++c) {
        int xv = cnt[tid][c];
        int inc = xv;
        #pragma unroll
        for (int d = 1; d < 64; d <<= 1) { int y = __shfl_up(inc, d); if (lane >= d) inc += y; }
        if (lane == 63) wtot[wv][c] = inc;
        cnt[tid][c] = inc - xv;
      }
      __syncthreads();
      if (tid == 0) {
        int run = 0;
        #pragma unroll
        for (int c = 0; c < NCLS; ++c) {
          int tot = wtot[0][c] + wtot[1][c] + wtot[2][c] + wtot[3][c];
          pstart[c] = run;
          int ntile = (tot + 63) >> 6;
          for (int tt = 0; tt < ntile; ++tt) tcls[(run >> 6) + tt] = c;
          run += ntile << 6;
        }
        for (int tt = run >> 6; tt < NT_PAD; ++tt) tcls[tt] = NCLS;
      }
      __syncthreads();
      #pragma unroll
      for (int c = 0; c < NCLS; ++c) {
        int add = pstart[c];
        for (int w2 = 0; w2 < 4; ++w2) if (w2 < wv) add += wtot[w2][c];
        cnt[tid][c] += add;
      }
      __syncthreads();
      for (int i = tid; i < NROWS; i += 256) {
        int c = yn[i];
        pidx[cnt[tid][c]++] = i;
      }
    }
  }
  __threadfence();
  grid.sync();

  // ================= P1: layer1 =================
  for (int job = blockIdx.x; job < 1024; job += nbl) {
    const int r0 = job * 16;
    const int b = (job < 512) ? 0 : 1;
    const float* xrow = ((b == 0) ? (x + (size_t)r0 * 256)
                                  : (xn + (size_t)(r0 - 8192) * 256))
                        + (size_t)l15 * 256;
    f32x4 acc0 = {0.f,0.f,0.f,0.f}, acc1 = {0.f,0.f,0.f,0.f};
    #pragma unroll
    for (int ks = 0; ks < 8; ++ks) {
      const float* xp = xrow + ks * 32 + l4 * 8;
      f32x4 a0 = *(const f32x4*)xp;
      f32x4 a1 = *(const f32x4*)(xp + 4);
      bf16x8 ah, al_;
      #pragma unroll
      for (int i = 0; i < 4; ++i) {
        u16 h = f2bf(a0[i]); ah[i] = (short)h; al_[i] = (short)f2bf(a0[i] - bf2f(h));
      }
      #pragma unroll
      for (int i = 0; i < 4; ++i) {
        u16 h = f2bf(a1[i]); ah[4+i] = (short)h; al_[4+i] = (short)f2bf(a1[i] - bf2f(h));
      }
      const u16* bbase = w0p + (size_t)(ks * 4 + l4) * 1024;
      {
        const int col = 32 * w + l15;
        bf16x8 bh = *(const bf16x8*)(bbase + col * 8);
        bf16x8 bl = *(const bf16x8*)(bbase + 32768 + col * 8);
        acc0 = __builtin_amdgcn_mfma_f32_16x16x32_bf16(ah, bh, acc0, 0, 0, 0);
        acc0 = __builtin_amdgcn_mfma_f32_16x16x32_bf16(ah, bl, acc0, 0, 0, 0);
        acc0 = __builtin_amdgcn_mfma_f32_16x16x32_bf16(al_, bh, acc0, 0, 0, 0);
      }
      {
        const int col = 32 * w + 16 + l15;
        bf16x8 bh = *(const bf16x8*)(bbase + col * 8);
        bf16x8 bl = *(const bf16x8*)(bbase + 32768 + col * 8);
        acc1 = __builtin_amdgcn_mfma_f32_16x16x32_bf16(ah, bh, acc1, 0, 0, 0);
        acc1 = __builtin_amdgcn_mfma_f32_16x16x32_bf16(ah, bl, acc1, 0, 0, 0);
        acc1 = __builtin_amdgcn_mfma_f32_16x16x32_bf16(al_, bh, acc1, 0, 0, 0);
      }
    }
    #pragma unroll
    for (int ct = 0; ct < 2; ++ct) {
      const f32x4 av = ct ? acc1 : acc0;
      const int col = 32 * w + 16 * ct + l15;
      const float bj = b0[col];
      float s = 0.f, q = 0.f;
      #pragma unroll
      for (int r = 0; r < 4; ++r) {
        float v = tanh_fast(av[r] + bj);
        const int row = r0 + 4 * l4 + r;
        u16 hi = f2bf(v);
        h1h[(size_t)row * 128 + col] = hi;
        h1l[(size_t)row * 128 + col] = f2bf(v - bf2f(hi));
        s += v; q += v * v;
      }
      s += __shfl_xor(s, 16); s += __shfl_xor(s, 32);
      q += __shfl_xor(q, 16); q += __shfl_xor(q, 32);
      if (l < 16) {
        AADD(&sums[b * 128 + col], s);
        AADD(&sums[256 + b * 128 + col], q);
      }
    }
  }
  __threadfence();
  grid.sync();

  // ================= P2: fold(BN1->W1eff in LDS) + layer2 =================
  for (int job = blockIdx.x; job < 1024; job += nbl) {
    const int r0 = job * 16;
    const int b = (job < 512) ? 0 : 1;
    u16*   w1l  = (u16*)SMEM;
    float* sc0s = (float*)(SMEM + 32768);
    float* sh0s = (float*)(SMEM + 33280);
    float* b1es = (float*)(SMEM + 33792);
    __syncthreads();
    if (tid < 128) {
      float s = sums[b * 128 + tid], q = sums[256 + b * 128 + tid];
      float m = s * (1.f / 8192.f);
      float v = q * (1.f / 8192.f) - m * m;
      float sc = g0[tid] * rsqrtf(v + EPSBN);
      sc0s[tid] = sc;
      sh0s[tid] = bt0[tid] - m * sc;
    }
    __syncthreads();
    for (int e = tid; e < 8192; e += 256) {
      const int j = e >> 6, o = e & 63;
      float wv = W1[o * 128 + j];
      float wsc = wv * sc0s[j];
      u16 hi = f2bf(wsc);
      w1l[(j >> 3) * 512 + o * 8 + (j & 7)] = hi;
      w1l[8192 + (j >> 3) * 512 + o * 8 + (j & 7)] = f2bf(wsc - bf2f(hi));
    }
    if (tid < 64) {
      float a = 0.f;
      for (int j = 0; j < 128; ++j) a = fmaf(W1[tid * 128 + j], sh0s[j], a);
      b1es[tid] = b1[tid] + a;
    }
    __syncthreads();

    const u16* arow_h = h1h + (size_t)(r0 + l15) * 128;
    const u16* arow_l = h1l + (size_t)(r0 + l15) * 128;
    f32x4 acc = {0.f,0.f,0.f,0.f};
    const int col = 16 * w + l15;
    #pragma unroll
    for (int ks = 0; ks < 4; ++ks) {
      bf16x8 ah = *(const bf16x8*)(arow_h + ks * 32 + l4 * 8);
      bf16x8 al_ = *(const bf16x8*)(arow_l + ks * 32 + l4 * 8);
      const u16* bb = w1l + (size_t)(ks * 4 + l4) * 512 + col * 8;
      bf16x8 bh = *(const bf16x8*)(bb);
      bf16x8 bl = *(const bf16x8*)(bb + 8192);
      acc = __builtin_amdgcn_mfma_f32_16x16x32_bf16(ah, bh, acc, 0, 0, 0);
      acc = __builtin_amdgcn_mfma_f32_16x16x32_bf16(ah, bl, acc, 0, 0, 0);
      acc = __builtin_amdgcn_mfma_f32_16x16x32_bf16(al_, bh, acc, 0, 0, 0);
    }
    const float bj = b1es[col];
    float s = 0.f, q = 0.f;
    #pragma unroll
    for (int r = 0; r < 4; ++r) {
      float v = tanh_fast(acc[r] + bj);
      h2[(size_t)(r0 + 4 * l4 + r) * 64 + col] = v;
      s += v; q += v * v;
    }
    s += __shfl_xor(s, 16); s += __shfl_xor(s, 32);
    q += __shfl_xor(q, 16); q += __shfl_xor(q, 32);
    if (l < 16) {
      AADD(&sums[512 + b * 64 + col], s);
      AADD(&sums[640 + b * 64 + col], q);
    }
  }
  __threadfence();
  grid.sync();

  // ================= P3: BN2 + bf16 split =================
  for (int job = blockIdx.x; job < 4256; job += nbl) {
    const int r = tid >> 6, o = tid & 63;
    const bool isq = (job < 2048);
    const int b = isq ? 0 : 1;
    float s = sums[512 + b * 64 + o], q = sums[640 + b * 64 + o];
    float m = s * (1.f / 8192.f);
    float v = q * (1.f / 8192.f) - m * m;
    float sc = g1[o] * rsqrtf(v + EPSBN);
    float sh = bt1[o] - m * sc;
    if (isq) {
      const int row = job * 4 + r;
      float vv = sc * h2[(size_t)row * 64 + o] + sh;
      u16 hi = f2bf(vv);
      qh[(size_t)row * 64 + o] = hi;
      ql[(size_t)row * 64 + o] = f2bf(vv - bf2f(hi));
      float sq = vv * vv;
      #pragma unroll
      for (int off = 32; off; off >>= 1) sq += __shfl_xor(sq, off);
      if (o == 0) qn2[row] = SCL * sq;
    } else {
      const int row = (job - 2048) * 4 + r;
      const int src = pidx[row];
      float vv = 0.f;
      if (src >= 0) vv = sc * h2[(size_t)(NROWS + src) * 64 + o] + sh;
      u16 hi = f2bf(vv);
      kh[(size_t)row * 64 + o] = hi;
      kl[(size_t)row * 64 + o] = f2bf(vv - bf2f(hi));
      float sq = vv * vv;
      #pragma unroll
      for (int off = 32; off; off >>= 1) sq += __shfl_xor(sq, off);
      if (o == 0) kn2[row] = (src >= 0) ? SCL * sq : 1e30f;
    }
  }
  __threadfence();
  grid.sync();

  // ================= P4: cdist + exp + per-class accumulation =================
  for (int job = blockIdx.x; job < 128 * GY; job += nbl) {
    u16 (*bs)[8192] = (u16(*)[8192])SMEM;
    float* cls_lds = (float*)(SMEM + 32768);
    const int n0 = (job & 127) * 64;
    const int g = job >> 7;
    const int t0 = (g * NT_PAD) / GY, t1 = ((g + 1) * NT_PAD) / GY;

    __syncthreads();
    for (int i = tid; i < 2 * (NCLS + 1) * 64; i += 256) cls_lds[i] = 0.f;

    const int lh = l >> 5;
    const int arow = n0 + 32 * (w >> 1) + (l & 31);
    bf16x8 aH[4], aL[4];
    #pragma unroll
    for (int j = 0; j < 4; ++j) {
      aH[j] = *(const bf16x8*)(qh + (size_t)arow * 64 + j * 16 + 8 * lh);
      aL[j] = *(const bf16x8*)(ql + (size_t)arow * 64 + j * 16 + 8 * lh);
    }
    float qnr[16];
    #pragma unroll
    for (int g4 = 0; g4 < 4; ++g4) {
      f32x4 qv = *(const f32x4*)(qn2 + n0 + 32 * (w >> 1) + 8 * g4 + 4 * lh);
      qnr[4*g4+0] = qv[0]; qnr[4*g4+1] = qv[1]; qnr[4*g4+2] = qv[2]; qnr[4*g4+3] = qv[3];
    }

    const int a_ = (l >> 3) & 1;
    const u16* sarr = a_ ? kl : kh;
    int soff[4];
    #pragma unroll
    for (int j = 0; j < 4; ++j) {
      const int col = 16 * w + 4 * j + (l >> 4);
      const int c8 = (l & 7) ^ (col & 7);
      soff[j] = col * 64 + c8 * 8;
    }
    const int colL = 32 * (w & 1) + (l & 31);
    const char* rb_base = (const char*)&bs[0][0] + colL * 256;
    const int c7r = colL & 7;

#define STAGE(TT, PB) do { const size_t tb_ = (size_t)(TT) * 4096; \
    u16* lb_ = &bs[PB][0] + (size_t)(w * 4) * 512; \
    glds16(sarr + tb_ + soff[0], lb_);        \
    glds16(sarr + tb_ + soff[1], lb_ + 512);  \
    glds16(sarr + tb_ + soff[2], lb_ + 1024); \
    glds16(sarr + tb_ + soff[3], lb_ + 1536); } while (0)

#define FLUSH(CC) do { \
    _Pragma("unroll") for (int r = 0; r < 16; ++r) { \
      run[r] += __shfl_xor(run[r], 1);  run[r] += __shfl_xor(run[r], 2); \
      run[r] += __shfl_xor(run[r], 4);  run[r] += __shfl_xor(run[r], 8); \
      run[r] += __shfl_xor(run[r], 16); } \
    if ((l & 31) == 0) { \
      float* cl_ = cls_lds + (w & 1) * 704 + (CC) * 64 + 32 * (w >> 1) + 4 * lh; \
      _Pragma("unroll") for (int r = 0; r < 16; ++r) cl_[(r & 3) + 8 * (r >> 2)] += run[r]; } \
    _Pragma("unroll") for (int r = 0; r < 16; ++r) run[r] = 0.f; } while (0)

    STAGE(t0, 0);

    float run[16];
    #pragma unroll
    for (int r = 0; r < 16; ++r) run[r] = 0.f;
    int ccur = tcls[t0];
    int p = 0;

    for (int t = t0; t < t1; ++t) {
      __syncthreads();
      if (t + 1 < t1) STAGE(t + 1, p ^ 1);
      const int c = tcls[t];
      if (c != ccur) { FLUSH(ccur); ccur = c; }
      const float kv = kn2[t * 64 + colL];

      f32x16 accA, accB;
      #pragma unroll
      for (int r = 0; r < 16; ++r) { accA[r] = 0.f; accB[r] = 0.f; }
      const char* pb = rb_base + p * 16384;
      #pragma unroll
      for (int j = 0; j < 4; ++j) {
        const int c8 = 2 * j + lh;
        bf16x8 bh  = *(const bf16x8*)(pb + ((c8 ^ c7r) << 4));
        bf16x8 bl_ = *(const bf16x8*)(pb + 128 + ((c8 ^ c7r) << 4));
        accA = __builtin_amdgcn_mfma_f32_32x32x16_bf16(aH[j], bh,  accA, 0, 0, 0);
        accB = __builtin_amdgcn_mfma_f32_32x32x16_bf16(aH[j], bl_, accB, 0, 0, 0);
        accA = __builtin_amdgcn_mfma_f32_32x32x16_bf16(aL[j], bh,  accA, 0, 0, 0);
      }
      #pragma unroll
      for (int r = 0; r < 16; ++r) {
        float d2 = fmaf(SCL2, accA[r] + accB[r], qnr[r] + kv);
        d2 = fmaxf(d2, 2.0813689e-12f);
        run[r] += __builtin_amdgcn_exp2f(-__builtin_amdgcn_sqrtf(d2));
      }
      p ^= 1;
    }
    FLUSH(ccur);
    __syncthreads();

    for (int i = tid; i < (NCLS + 1) * 64; i += 256) {
      const int c = i >> 6, rr = i & 63;
      part[((size_t)g * (NCLS + 1) + c) * NROWS + n0 + rr] = cls_lds[i] + cls_lds[704 + i];
    }
    __syncthreads();
#undef STAGE
#undef FLUSH
  }
  __threadfence();
  grid.sync();

  // ================= P5: finalize =================
  for (int job = blockIdx.x; job < 32; job += nbl) {
    const int n = job * 256 + tid;
    float sc[NCLS];
    #pragma unroll
    for (int c = 0; c < NCLS; ++c) sc[c] = 0.f;
    for (int g = 0; g < GY; ++g) {
      #pragma unroll
      for (int c = 0; c < NCLS; ++c)
        sc[c] += part[((size_t)g * (NCLS + 1) + c) * NROWS + n];
    }
    float tot = 0.f;
    #pragma unroll
    for (int c = 0; c < NCLS; ++c) tot += sc[c];
    const float inv = 1.f / tot;
    #pragma unroll
    for (int c = 0; c < NCLS; ++c)
      out[(size_t)n * NCLS + c] = fminf(fmaxf(sc[c] * inv, 0.f), 1.f);
  }
}

// ============================================================================
// FALLBACK: R5 multi-kernel pipeline (known-good)
// ============================================================================
__global__ __launch_bounds__(256) void k_prep(
    const float* __restrict__ w0, const int* __restrict__ yn,
    u16* __restrict__ w0p, int* __restrict__ pidx, int* __restrict__ tcls,
    float* __restrict__ sums)
{
  if (blockIdx.x < 128) {
    int idx = blockIdx.x * 256 + threadIdx.x;
    int t = idx & 255;
    float v = w0[idx];
    u16 hi = f2bf(v);
    u16 lo = f2bf(v - bf2f(hi));
    int j = idx >> 8;
    w0p[(t >> 3) * 1024 + j * 8 + (t & 7)] = hi;
    w0p[32768 + (t >> 3) * 1024 + j * 8 + (t & 7)] = lo;
    return;
  }
  __shared__ int cnt[256][NCLS];
  __shared__ int wtot[4][NCLS];
  __shared__ int pstart[NCLS + 1];
  const int t = threadIdx.x;
  const int lane = t & 63, wv = t >> 6;
  sums[t] = 0.f; sums[t + 256] = 0.f; sums[t + 512] = 0.f;
  #pragma unroll
  for (int c = 0; c < NCLS; ++c) cnt[t][c] = 0;
  for (int i = t; i < MPAD; i += 256) pidx[i] = -1;
  for (int i = t; i < NROWS; i += 256) cnt[t][yn[i]]++;
  __syncthreads();
  #pragma unroll
  for (int c = 0; c < NCLS; ++c) {
    int x = cnt[t][c];
    int inc = x;
    #pragma unroll
    for (int d = 1; d < 64; d <<= 1) { int y = __shfl_up(inc, d); if (lane >= d) inc += y; }
    if (lane == 63) wtot[wv][c] = inc;
    cnt[t][c] = inc - x;
  }
  __syncthreads();
  if (t == 0) {
    int run = 0;
    #pragma unroll
    for (int c = 0; c < NCLS; ++c) {
      int tot = wtot[0][c] + wtot[1][c] + wtot[2][c] + wtot[3][c];
      pstart[c] = run;
      int ntile = (tot + 63) >> 6;
      for (int tt = 0; tt < ntile; ++tt) tcls[(run >> 6) + tt] = c;
      run += ntile << 6;
    }
    pstart[NCLS] = run;
    for (int tt = run >> 6; tt < NT_PAD; ++tt) tcls[tt] = NCLS;
  }
  __syncthreads();
  #pragma unroll
  for (int c = 0; c < NCLS; ++c) {
    int add = pstart[c];
    for (int w2 = 0; w2 < 4; ++w2) if (w2 < wv) add += wtot[w2][c];
    cnt[t][c] += add;
  }
  __syncthreads();
  for (int i = t; i < NROWS; i += 256) {
    int c = yn[i];
    pidx[cnt[t][c]++] = i;
  }
}

__global__ __launch_bounds__(256) void k_layer1(
    const float* __restrict__ x, const float* __restrict__ xn,
    const u16* __restrict__ w0p, const float* __restrict__ b0,
    u16* __restrict__ h1h, u16* __restrict__ h1l, float* __restrict__ sums)
{
  const int tid = threadIdx.x;
  const int w = tid >> 6, l = tid & 63;
  const int l15 = l & 15, l4 = l >> 4;
  const int blk = blockIdx.x;
  const int rowHalf = w & 1, colHalf = w >> 1;
  const int r0 = blk * 32 + 16 * rowHalf;
  const int c0 = 64 * colHalf;
  const int b = (blk < 256) ? 0 : 1;
  const float* src = (blk < 256) ? (x + (size_t)blk * 32 * 256)
                                 : (xn + (size_t)(blk - 256) * 32 * 256);
  const float* xrow = src + (size_t)(16 * rowHalf + l15) * 256;

  f32x4 acc[4];
  #pragma unroll
  for (int ct = 0; ct < 4; ++ct) acc[ct] = (f32x4){0.f, 0.f, 0.f, 0.f};

  #pragma unroll
  for (int ks = 0; ks < 8; ++ks) {
    const float* xp = xrow + ks * 32 + l4 * 8;
    f32x4 a0 = *(const f32x4*)xp;
    f32x4 a1 = *(const f32x4*)(xp + 4);
    bf16x8 ah, al_;
    #pragma unroll
    for (int i = 0; i < 4; ++i) {
      u16 h = f2bf(a0[i]); ah[i] = (short)h; al_[i] = (short)f2bf(a0[i] - bf2f(h));
    }
    #pragma unroll
    for (int i = 0; i < 4; ++i) {
      u16 h = f2bf(a1[i]); ah[4 + i] = (short)h; al_[4 + i] = (short)f2bf(a1[i] - bf2f(h));
    }
    const u16* bbase = w0p + (size_t)(ks * 4 + l4) * 1024;
    #pragma unroll
    for (int ct = 0; ct < 4; ++ct) {
      const int col = c0 + 16 * ct + l15;
      bf16x8 bh = *(const bf16x8*)(bbase + col * 8);
      bf16x8 bl = *(const bf16x8*)(bbase + 32768 + col * 8);
      acc[ct] = __builtin_amdgcn_mfma_f32_16x16x32_bf16(ah, bh, acc[ct], 0, 0, 0);
      acc[ct] = __builtin_amdgcn_mfma_f32_16x16x32_bf16(ah, bl, acc[ct], 0, 0, 0);
      acc[ct] = __builtin_amdgcn_mfma_f32_16x16x32_bf16(al_, bh, acc[ct], 0, 0, 0);
    }
  }

  #pragma unroll
  for (int ct = 0; ct < 4; ++ct) {
    const int col = c0 + 16 * ct + l15;
    const float bj = b0[col];
    float s = 0.f, q = 0.f;
    #pragma unroll
    for (int r = 0; r < 4; ++r) {
      float v = tanh_fast(acc[ct][r] + bj);
      const int row = r0 + 4 * l4 + r;
      u16 hi = f2bf(v);
      h1h[(size_t)row * 128 + col] = hi;
      h1l[(size_t)row * 128 + col] = f2bf(v - bf2f(hi));
      s += v; q += v * v;
    }
    s += __shfl_xor(s, 16); s += __shfl_xor(s, 32);
    q += __shfl_xor(q, 16); q += __shfl_xor(q, 32);
    if (l < 16) {
      AADD(&sums[b * 128 + col], s);
      AADD(&sums[256 + b * 128 + col], q);
    }
  }
}

__global__ __launch_bounds__(128) void k_foldp(
    const float* __restrict__ w1, const float* __restrict__ b1,
    const float* __restrict__ g0, const float* __restrict__ bt0,
    const float* __restrict__ sums, u16* __restrict__ w1p, float* __restrict__ b1e)
{
  const int o = blockIdx.x;
  const int j = threadIdx.x;
  __shared__ float red[2][2];
  const float w = w1[o * 128 + j];
  #pragma unroll
  for (int b = 0; b < 2; ++b) {
    float s = sums[b * 128 + j], q = sums[256 + b * 128 + j];
    float m = s * (1.f / 8192.f);
    float v = q * (1.f / 8192.f) - m * m;
    float sc = g0[j] * rsqrtf(v + EPSBN);
    float sh = bt0[j] - m * sc;
    float wsc = w * sc;
    u16 hi = f2bf(wsc);
    u16 lo = f2bf(wsc - bf2f(hi));
    w1p[((size_t)(b * 2 + 0) * 16 + (j >> 3)) * 512 + o * 8 + (j & 7)] = hi;
    w1p[((size_t)(b * 2 + 1) * 16 + (j >> 3)) * 512 + o * 8 + (j & 7)] = lo;
    float a = w * sh;
    #pragma unroll
    for (int off = 32; off; off >>= 1) a += __shfl_xor(a, off);
    if ((j & 63) == 0) red[j >> 6][b] = a;
  }
  __syncthreads();
  if (j < 2) b1e[j * 64 + o] = b1[o] + red[0][j] + red[1][j];
}

__global__ __launch_bounds__(256) void k_layer2(
    const u16* __restrict__ h1h, const u16* __restrict__ h1l,
    const u16* __restrict__ w1p, const float* __restrict__ b1e,
    float* __restrict__ h2, float* __restrict__ sums)
{
  const int tid = threadIdx.x;
  const int w = tid >> 6, l = tid & 63;
  const int l15 = l & 15, l4 = l >> 4;
  const int blk = blockIdx.x;
  const int rowHalf = w & 1, colHalf = w >> 1;
  const int r0 = blk * 32 + 16 * rowHalf;
  const int c0 = 32 * colHalf;
  const int b = blk >> 8;
  const u16* arow_h = h1h + (size_t)(r0 + l15) * 128;
  const u16* arow_l = h1l + (size_t)(r0 + l15) * 128;

  f32x4 acc[2];
  acc[0] = (f32x4){0.f, 0.f, 0.f, 0.f};
  acc[1] = (f32x4){0.f, 0.f, 0.f, 0.f};

  #pragma unroll
  for (int ks = 0; ks < 4; ++ks) {
    bf16x8 ah = *(const bf16x8*)(arow_h + ks * 32 + l4 * 8);
    bf16x8 al_ = *(const bf16x8*)(arow_l + ks * 32 + l4 * 8);
    const u16* bb = w1p + ((size_t)(b * 2) * 16 + ks * 4 + l4) * 512;
    #pragma unroll
    for (int ct = 0; ct < 2; ++ct) {
      const int col = c0 + 16 * ct + l15;
      bf16x8 bh = *(const bf16x8*)(bb + col * 8);
      bf16x8 bl = *(const bf16x8*)(bb + 8192 + col * 8);
      acc[ct] = __builtin_amdgcn_mfma_f32_16x16x32_bf16(ah, bh, acc[ct], 0, 0, 0);
      acc[ct] = __builtin_amdgcn_mfma_f32_16x16x32_bf16(ah, bl, acc[ct], 0, 0, 0);
      acc[ct] = __builtin_amdgcn_mfma_f32_16x16x32_bf16(al_, bh, acc[ct], 0, 0, 0);
    }
  }

  #pragma unroll
  for (int ct = 0; ct < 2; ++ct) {
    const int col = c0 + 16 * ct + l15;
    const float bj = b1e[b * 64 + col];
    float s = 0.f, q = 0.f;
    #pragma unroll
    for (int r = 0; r < 4; ++r) {
      float v = tanh_fast(acc[ct][r] + bj);
      const int row = r0 + 4 * l4 + r;
      h2[(size_t)row * 64 + col] = v;
      s += v; q += v * v;
    }
    s += __shfl_xor(s, 16); s += __shfl_xor(s, 32);
    q += __shfl_xor(q, 16); q += __shfl_xor(q, 32);
    if (l < 16) {
      AADD(&sums[512 + b * 64 + col], s);
      AADD(&sums[640 + b * 64 + col], q);
    }
  }
}

__global__ __launch_bounds__(256) void k_bn2(
    const float* __restrict__ h2, const float* __restrict__ sums,
    const float* __restrict__ g1, const float* __restrict__ bt1,
    const int* __restrict__ pidx,
    u16* __restrict__ qh, u16* __restrict__ ql, float* __restrict__ qn2,
    u16* __restrict__ kh, u16* __restrict__ kl, float* __restrict__ kn2)
{
  const int tid = threadIdx.x;
  const int r = tid >> 6, o = tid & 63;
  const bool isq = (blockIdx.x < 2048);
  const int b = isq ? 0 : 1;
  float s = sums[512 + b * 64 + o], q = sums[640 + b * 64 + o];
  float m = s * (1.f / 8192.f);
  float v = q * (1.f / 8192.f) - m * m;
  float sc = g1[o] * rsqrtf(v + EPSBN);
  float sh = bt1[o] - m * sc;
  if (isq) {
    const int row = blockIdx.x * 4 + r;
    float vv = sc * h2[(size_t)row * 64 + o] + sh;
    u16 hi = f2bf(vv);
    qh[(size_t)row * 64 + o] = hi;
    ql[(size_t)row * 64 + o] = f2bf(vv - bf2f(hi));
    float sq = vv * vv;
    #pragma unroll
    for (int off = 32; off; off >>= 1) sq += __shfl_xor(sq, off);
    if (o == 0) qn2[row] = SCL * sq;
  } else {
    const int row = (blockIdx.x - 2048) * 4 + r;
    const int src = pidx[row];
    float vv = 0.f;
    if (src >= 0) vv = sc * h2[(size_t)(NROWS + src) * 64 + o] + sh;
    u16 hi = f2bf(vv);
    kh[(size_t)row * 64 + o] = hi;
    kl[(size_t)row * 64 + o] = f2bf(vv - bf2f(hi));
    float sq = vv * vv;
    #pragma unroll
    for (int off = 32; off; off >>= 1) sq += __shfl_xor(sq, off);
    if (o == 0) kn2[row] = (src >= 0) ? SCL * sq : 1e30f;
  }
}

__global__ __launch_bounds__(256, 4) void k_dist(
    const u16* __restrict__ qh, const u16* __restrict__ ql, const float* __restrict__ qn2,
    const u16* __restrict__ kh, const u16* __restrict__ kl, const float* __restrict__ kn2,
    const int* __restrict__ tcls, float* __restrict__ part)
{
  __shared__ u16 bs[2][8192];
  __shared__ float cls_lds[2 * (NCLS + 1) * 64];
  const int tid = threadIdx.x;
  const int w = tid >> 6, l = tid & 63;
  const int n0 = blockIdx.x * 64;
  const int g = blockIdx.y;
  const int t0 = (g * NT_PAD) / GY, t1 = ((g + 1) * NT_PAD) / GY;

  for (int i = tid; i < 2 * (NCLS + 1) * 64; i += 256) cls_lds[i] = 0.f;

  const int lh = l >> 5;
  const int arow = n0 + 32 * (w >> 1) + (l & 31);
  bf16x8 aH[4], aL[4];
  #pragma unroll
  for (int j = 0; j < 4; ++j) {
    aH[j] = *(const bf16x8*)(qh + (size_t)arow * 64 + j * 16 + 8 * lh);
    aL[j] = *(const bf16x8*)(ql + (size_t)arow * 64 + j * 16 + 8 * lh);
  }
  float qnr[16];
  #pragma unroll
  for (int g4 = 0; g4 < 4; ++g4) {
    f32x4 qv = *(const f32x4*)(qn2 + n0 + 32 * (w >> 1) + 8 * g4 + 4 * lh);
    qnr[4*g4+0] = qv[0]; qnr[4*g4+1] = qv[1]; qnr[4*g4+2] = qv[2]; qnr[4*g4+3] = qv[3];
  }

  const int a_ = (l >> 3) & 1;
  const u16* sarr = a_ ? kl : kh;
  int soff[4];
  #pragma unroll
  for (int j = 0; j < 4; ++j) {
    const int col = 16 * w + 4 * j + (l >> 4);
    const int c8 = (l & 7) ^ (col & 7);
    soff[j] = col * 64 + c8 * 8;
  }
  const int colL = 32 * (w & 1) + (l & 31);
  const char* rb_base = (const char*)&bs[0][0] + colL * 256;
  const int c7r = colL & 7;

#define STAGE(TT, PB) do { const size_t tb_ = (size_t)(TT) * 4096; \
    u16* lb_ = &bs[PB][0] + (size_t)(w * 4) * 512; \
    glds16(sarr + tb_ + soff[0], lb_);        \
    glds16(sarr + tb_ + soff[1], lb_ + 512);  \
    glds16(sarr + tb_ + soff[2], lb_ + 1024); \
    glds16(sarr + tb_ + soff[3], lb_ + 1536); } while (0)

#define FLUSH(CC) do { \
    _Pragma("unroll") for (int r = 0; r < 16; ++r) { \
      run[r] += __shfl_xor(run[r], 1);  run[r] += __shfl_xor(run[r], 2); \
      run[r] += __shfl_xor(run[r], 4);  run[r] += __shfl_xor(run[r], 8); \
      run[r] += __shfl_xor(run[r], 16); } \
    if ((l & 31) == 0) { \
      float* cl_ = cls_lds + (w & 1) * 704 + (CC) * 64 + 32 * (w >> 1) + 4 * lh; \
      _Pragma("unroll") for (int r = 0; r < 16; ++r) cl_[(r & 3) + 8 * (r >> 2)] += run[r]; } \
    _Pragma("unroll") for (int r = 0; r < 16; ++r) run[r] = 0.f; } while (0)

  STAGE(t0, 0);

  float run[16];
  #pragma unroll
  for (int r = 0; r < 16; ++r) run[r] = 0.f;
  int ccur = tcls[t0];
  int p = 0;

  for (int t = t0; t < t1; ++t) {
    __syncthreads();
    if (t + 1 < t1) STAGE(t + 1, p ^ 1);
    const int c = tcls[t];
    if (c != ccur) { FLUSH(ccur); ccur = c; }
    const float kv = kn2[t * 64 + colL];

    f32x16 accA, accB;
    #pragma unroll
    for (int r = 0; r < 16; ++r) { accA[r] = 0.f; accB[r] = 0.f; }
    const char* pb = rb_base + p * 16384;
    #pragma unroll
    for (int j = 0; j < 4; ++j) {
      const int c8 = 2 * j + lh;
      bf16x8 bh  = *(const bf16x8*)(pb + ((c8 ^ c7r) << 4));
      bf16x8 bl_ = *(const bf16x8*)(pb + 128 + ((c8 ^ c7r) << 4));
      accA = __builtin_amdgcn_mfma_f32_32x32x16_bf16(aH[j], bh,  accA, 0, 0, 0);
      accB = __builtin_amdgcn_mfma_f32_32x32x16_bf16(aH[j], bl_, accB, 0, 0, 0);
      accA = __builtin_amdgcn_mfma_f32_32x32x16_bf16(aL[j], bh,  accA, 0, 0, 0);
    }
    #pragma unroll
    for (int r = 0; r < 16; ++r) {
      float d2 = fmaf(SCL2, accA[r] + accB[r], qnr[r] + kv);
      d2 = fmaxf(d2, 2.0813689e-12f);
      run[r] += __builtin_amdgcn_exp2f(-__builtin_amdgcn_sqrtf(d2));
    }
    p ^= 1;
  }
  FLUSH(ccur);
  __syncthreads();

  for (int i = tid; i < (NCLS + 1) * 64; i += 256) {
    const int c = i >> 6, rr = i & 63;
    part[((size_t)g * (NCLS + 1) + c) * NROWS + n0 + rr] = cls_lds[i] + cls_lds[704 + i];
  }
#undef STAGE
#undef FLUSH
}

__global__ __launch_bounds__(256) void k_final(const float* __restrict__ part,
                                               float* __restrict__ out)
{
  const int n = blockIdx.x * 256 + threadIdx.x;
  float sc[NCLS];
  #pragma unroll
  for (int c = 0; c < NCLS; ++c) sc[c] = 0.f;
  for (int g = 0; g < GY; ++g) {
    #pragma unroll
    for (int c = 0; c < NCLS; ++c)
      sc[c] += part[((size_t)g * (NCLS + 1) + c) * NROWS + n];
  }
  float tot = 0.f;
  #pragma unroll
  for (int c = 0; c < NCLS; ++c) tot += sc[c];
  const float inv = 1.f / tot;
  #pragma unroll
  for (int c = 0; c < NCLS; ++c)
    out[(size_t)n * NCLS + c] = fminf(fmaxf(sc[c] * inv, 0.f), 1.f);
}

extern "C" void kernel_launch(void* const* d_in, const int* in_sizes, int n_in,
                              void* d_out, int out_size, void* d_ws, size_t ws_size,
                              hipStream_t stream) {
  const float* x   = (const float*)d_in[0];
  const float* xn  = (const float*)d_in[1];
  const int*   yn  = (const int*)d_in[2];
  const float* W0  = (const float*)d_in[3];
  const float* b0  = (const float*)d_in[4];
  const float* g0  = (const float*)d_in[5];
  const float* bt0 = (const float*)d_in[6];
  const float* W1  = (const float*)d_in[7];
  const float* b1  = (const float*)d_in[8];
  const float* g1  = (const float*)d_in[9];
  const float* bt1 = (const float*)d_in[10];
  float* out = (float*)d_out;
  float* ws  = (float*)d_ws;

  // Size the cooperative grid from the occupancy query (capture-safe host query).
  bool mega_ok = false;
  int perCU = 0;
  if (hipOccupancyMaxActiveBlocksPerMultiprocessor(&perCU, (const void*)k_mega, 256, 0)
          == hipSuccess && perCU > 0) {
    int nblocks = perCU * 256;          // 256 CUs on MI355X
    if (nblocks > 1024) nblocks = 1024;
    void* args[] = {&x, &xn, &yn, &W0, &b0, &g0, &bt0, &W1, &b1, &g1, &bt1, &ws, &out};
    mega_ok = (hipLaunchCooperativeKernel((const void*)k_mega, dim3(nblocks), dim3(256),
                                          args, 0, stream) == hipSuccess);
  }
  if (mega_ok) return;

  // -------- fallback: R5 multi-kernel pipeline --------
  u16*   w0pp = (u16*)(ws + FB_W0P);
  u16*   h1hp = (u16*)(ws + FB_H1H);
  u16*   h1lp = (u16*)(ws + FB_H1L);
  float* sumsp= ws + FB_SUM;
  u16*   w1pp = (u16*)(ws + FB_W1P);
  float* b1ep = ws + FB_B1E;
  float* h2p  = ws + FB_H2;
  int*   pidxp= (int*)(ws + FB_PIDX);
  int*   tclsp= (int*)(ws + FB_TCLS);
  u16*   qhp  = (u16*)(ws + FB_QH);
  u16*   qlp  = (u16*)(ws + FB_QL);
  float* qn2p = ws + FB_QN2;
  u16*   khp  = (u16*)(ws + FB_KH);
  u16*   klp  = (u16*)(ws + FB_KL);
  float* kn2p = ws + FB_KN2;
  float* partp= ws + FB_PART;

  k_prep<<<129, 256, 0, stream>>>(W0, yn, w0pp, pidxp, tclsp, sumsp);
  k_layer1<<<512, 256, 0, stream>>>(x, xn, w0pp, b0, h1hp, h1lp, sumsp);
  k_foldp<<<64, 128, 0, stream>>>(W1, b1, g0, bt0, sumsp, w1pp, b1ep);
  k_layer2<<<512, 256, 0, stream>>>(h1hp, h1lp, w1pp, b1ep, h2p, sumsp);
  k_bn2<<<2048 + MPAD / 4, 256, 0, stream>>>(h2p, sumsp, g1, bt1, pidxp,
                                             qhp, qlp, qn2p, khp, klp, kn2p);
  k_dist<<<dim3(128, GY), 256, 0, stream>>>(qhp, qlp, qn2p, khp, klp, kn2p, tclsp, partp);
  k_final<<<32, 256, 0, stream>>>(partp, out);
}

// Round 8
// 184.630 us; speedup vs baseline: 3.7625x; 3.7625x over previous
//
#include <hip/hip_runtime.h>
#include <math.h>

#define EPSBN 1e-5f
#define AADD(p, v) __hip_atomic_fetch_add((p), (v), __ATOMIC_RELAXED, __HIP_MEMORY_SCOPE_AGENT)

typedef unsigned short u16;
typedef short bf16x8 __attribute__((ext_vector_type(8)));
typedef float f32x4 __attribute__((ext_vector_type(4)));
typedef float f32x16 __attribute__((ext_vector_type(16)));

constexpr int NROWS = 8192;
constexpr int NCLS = 10;
constexpr int MPAD = 8832;        // 138 tiles of 64
constexpr int NT_PAD = 138;
constexpr int NST = 69;           // super-tiles of 128 K-rows
constexpr int GY = 8;
constexpr float SCL  = 2.0813689810056077f;   // (log2 e)^2
constexpr float SCL2 = -4.1627379620112154f;  // -2*(log2 e)^2

// workspace offsets (floats)
constexpr size_t OFF_W0P = 0;                      // u16[65536]
constexpr size_t OFF_H1H = 32768;                  // u16[16384*128] = 1048576 f
constexpr size_t OFF_H1L = OFF_H1H + 1048576;
constexpr size_t OFF_SUM = OFF_H1L + 1048576;      // 768 f (zeroed by memset)
constexpr size_t OFF_CNT = OFF_SUM + 768;          // 160 ints (cnt1 + cntd[128], zeroed)
constexpr size_t OFF_W1P = OFF_CNT + 160;          // u16[32768]
constexpr size_t OFF_B1E = OFF_W1P + 16384;        // 128 f
constexpr size_t OFF_H2  = OFF_B1E + 128;          // 16384*64 f
constexpr size_t OFF_PIDX = OFF_H2 + 1048576;      // int[8832]
constexpr size_t OFF_TCLS = OFF_PIDX + MPAD;       // int[144]
// overlays over h1 (dead after layer2)
constexpr size_t OFF_QB  = OFF_H1H;                // u16[8192*64]  = 262144 f
constexpr size_t OFF_KB  = OFF_QB + 262144;        // u16[8832*64]  = 282624 f
constexpr size_t OFF_QN2 = OFF_KB + 282624;        // 8192 f
constexpr size_t OFF_KN2 = OFF_QN2 + NROWS;        // 8832 f  (ends < OFF_SUM)
// part over h2 (dead after bn2): 8*11*8192 = 720896 <= 1048576
constexpr size_t OFF_PART = OFF_H2;

__device__ inline u16 f2bf(float f) {
  unsigned u = __float_as_uint(f);
  unsigned r = (u + 0x7fffu + ((u >> 16) & 1u)) >> 16;
  return (u16)r;
}
__device__ inline float bf2f(u16 h) { return __uint_as_float(((unsigned)h) << 16); }

__device__ inline float tanh_fast(float x) {
  float e = __builtin_amdgcn_exp2f(x * 2.88539008f);
  return 1.f - 2.f * __builtin_amdgcn_rcpf(e + 1.f);
}

__device__ inline void glds16(const u16* g, u16* l) {
  __builtin_amdgcn_global_load_lds(
      (const __attribute__((address_space(1))) unsigned int*)g,
      (__attribute__((address_space(3))) unsigned int*)l, 16, 0, 0);
}

// ---------------- prep: W0 pack (blocks 0-127) + class sort (block 128) ----------
__global__ __launch_bounds__(256) void k_prep(
    const float* __restrict__ w0, const int* __restrict__ yn,
    u16* __restrict__ w0p, int* __restrict__ pidx, int* __restrict__ tcls)
{
  if (blockIdx.x < 128) {
    int idx = blockIdx.x * 256 + threadIdx.x;
    int t = idx & 255;
    float v = w0[idx];
    u16 hi = f2bf(v);
    u16 lo = f2bf(v - bf2f(hi));
    int j = idx >> 8;
    w0p[(t >> 3) * 1024 + j * 8 + (t & 7)] = hi;
    w0p[32768 + (t >> 3) * 1024 + j * 8 + (t & 7)] = lo;
    return;
  }
  __shared__ int cnt[256][NCLS];
  __shared__ int wtot[4][NCLS];
  __shared__ int pstart[NCLS + 1];
  const int t = threadIdx.x;
  const int lane = t & 63, wv = t >> 6;
  #pragma unroll
  for (int c = 0; c < NCLS; ++c) cnt[t][c] = 0;
  for (int i = t; i < MPAD; i += 256) pidx[i] = -1;
  for (int i = t; i < NROWS; i += 256) cnt[t][yn[i]]++;
  __syncthreads();
  #pragma unroll
  for (int c = 0; c < NCLS; ++c) {
    int x = cnt[t][c];
    int inc = x;
    #pragma unroll
    for (int d = 1; d < 64; d <<= 1) { int y = __shfl_up(inc, d); if (lane >= d) inc += y; }
    if (lane == 63) wtot[wv][c] = inc;
    cnt[t][c] = inc - x;
  }
  __syncthreads();
  if (t == 0) {
    int run = 0;
    #pragma unroll
    for (int c = 0; c < NCLS; ++c) {
      int tot = wtot[0][c] + wtot[1][c] + wtot[2][c] + wtot[3][c];
      pstart[c] = run;
      int ntile = (tot + 63) >> 6;
      for (int tt = 0; tt < ntile; ++tt) tcls[(run >> 6) + tt] = c;
      run += ntile << 6;
    }
    pstart[NCLS] = run;
    for (int tt = run >> 6; tt < NT_PAD; ++tt) tcls[tt] = NCLS;
  }
  __syncthreads();
  #pragma unroll
  for (int c = 0; c < NCLS; ++c) {
    int add = pstart[c];
    for (int w2 = 0; w2 < 4; ++w2) if (w2 < wv) add += wtot[w2][c];
    cnt[t][c] += add;
  }
  __syncthreads();
  for (int i = t; i < NROWS; i += 256) {
    int c = yn[i];
    pidx[cnt[t][c]++] = i;
  }
}

// ---------------- layer 1 (3-pass MFMA) + BN1-fold tail in last block ------------
__global__ __launch_bounds__(256) void k_layer1(
    const float* __restrict__ x, const float* __restrict__ xn,
    const u16* __restrict__ w0p, const float* __restrict__ b0,
    const float* __restrict__ W1, const float* __restrict__ b1,
    const float* __restrict__ g0, const float* __restrict__ bt0,
    u16* __restrict__ h1h, u16* __restrict__ h1l, float* __restrict__ sums,
    u16* __restrict__ w1p, float* __restrict__ b1e, int* __restrict__ cnt1)
{
  const int tid = threadIdx.x;
  const int w = tid >> 6, l = tid & 63;
  const int l15 = l & 15, l4 = l >> 4;
  const int blk = blockIdx.x;                 // 512
  const int rowHalf = w & 1, colHalf = w >> 1;
  const int r0 = blk * 32 + 16 * rowHalf;
  const int c0 = 64 * colHalf;
  const int b = (blk < 256) ? 0 : 1;
  const float* src = (blk < 256) ? (x + (size_t)blk * 32 * 256)
                                 : (xn + (size_t)(blk - 256) * 32 * 256);
  const float* xrow = src + (size_t)(16 * rowHalf + l15) * 256;

  f32x4 acc[4];
  #pragma unroll
  for (int ct = 0; ct < 4; ++ct) acc[ct] = (f32x4){0.f, 0.f, 0.f, 0.f};

  #pragma unroll
  for (int ks = 0; ks < 8; ++ks) {
    const float* xp = xrow + ks * 32 + l4 * 8;
    f32x4 a0 = *(const f32x4*)xp;
    f32x4 a1 = *(const f32x4*)(xp + 4);
    bf16x8 ah, al_;
    #pragma unroll
    for (int i = 0; i < 4; ++i) {
      u16 h = f2bf(a0[i]); ah[i] = (short)h; al_[i] = (short)f2bf(a0[i] - bf2f(h));
    }
    #pragma unroll
    for (int i = 0; i < 4; ++i) {
      u16 h = f2bf(a1[i]); ah[4 + i] = (short)h; al_[4 + i] = (short)f2bf(a1[i] - bf2f(h));
    }
    const u16* bbase = w0p + (size_t)(ks * 4 + l4) * 1024;
    #pragma unroll
    for (int ct = 0; ct < 4; ++ct) {
      const int col = c0 + 16 * ct + l15;
      bf16x8 bh = *(const bf16x8*)(bbase + col * 8);
      bf16x8 bl = *(const bf16x8*)(bbase + 32768 + col * 8);
      acc[ct] = __builtin_amdgcn_mfma_f32_16x16x32_bf16(ah, bh, acc[ct], 0, 0, 0);
      acc[ct] = __builtin_amdgcn_mfma_f32_16x16x32_bf16(ah, bl, acc[ct], 0, 0, 0);
      acc[ct] = __builtin_amdgcn_mfma_f32_16x16x32_bf16(al_, bh, acc[ct], 0, 0, 0);
    }
  }

  #pragma unroll
  for (int ct = 0; ct < 4; ++ct) {
    const int col = c0 + 16 * ct + l15;
    const float bj = b0[col];
    float s = 0.f, q = 0.f;
    #pragma unroll
    for (int r = 0; r < 4; ++r) {
      float v = tanh_fast(acc[ct][r] + bj);
      const int row = r0 + 4 * l4 + r;
      u16 hi = f2bf(v);
      h1h[(size_t)row * 128 + col] = hi;
      h1l[(size_t)row * 128 + col] = f2bf(v - bf2f(hi));
      s += v; q += v * v;
    }
    s += __shfl_xor(s, 16); s += __shfl_xor(s, 32);
    q += __shfl_xor(q, 16); q += __shfl_xor(q, 32);
    if (l < 16) {
      AADD(&sums[b * 128 + col], s);
      AADD(&sums[256 + b * 128 + col], q);
    }
  }

  // ---- last-block tail: fold BN1 into W1 (replaces k_foldp launch) ----
  __shared__ int lastflag;
  __syncthreads();   // drains each thread's atomics (vmcnt) before counter release
  if (tid == 0) {
    int old = __hip_atomic_fetch_add(cnt1, 1, __ATOMIC_ACQ_REL, __HIP_MEMORY_SCOPE_AGENT);
    lastflag = (old == 511) ? 1 : 0;
  }
  __syncthreads();
  if (!lastflag) return;

  __shared__ float sc0s[2][128], sh0s[2][128];
  {
    int bb = tid >> 7, j = tid & 127;
    float s = __hip_atomic_load(&sums[bb * 128 + j], __ATOMIC_RELAXED, __HIP_MEMORY_SCOPE_AGENT);
    float q = __hip_atomic_load(&sums[256 + bb * 128 + j], __ATOMIC_RELAXED, __HIP_MEMORY_SCOPE_AGENT);
    float m = s * (1.f / 8192.f);
    float v = q * (1.f / 8192.f) - m * m;
    float sc = g0[j] * rsqrtf(v + EPSBN);
    sc0s[bb][j] = sc;
    sh0s[bb][j] = bt0[j] - m * sc;
  }
  __syncthreads();
  {
    const int o = tid >> 2, pt = tid & 3;
    float a0 = 0.f, a1 = 0.f;
    for (int jj = 0; jj < 32; ++jj) {
      int j = pt * 32 + jj;
      float wv = W1[o * 128 + j];
      float w0_ = wv * sc0s[0][j];
      float w1_ = wv * sc0s[1][j];
      u16 h0 = f2bf(w0_), h1_ = f2bf(w1_);
      w1p[((size_t)(j >> 3)) * 512 + o * 8 + (j & 7)] = h0;
      w1p[((size_t)(16 + (j >> 3))) * 512 + o * 8 + (j & 7)] = f2bf(w0_ - bf2f(h0));
      w1p[((size_t)(32 + (j >> 3))) * 512 + o * 8 + (j & 7)] = h1_;
      w1p[((size_t)(48 + (j >> 3))) * 512 + o * 8 + (j & 7)] = f2bf(w1_ - bf2f(h1_));
      a0 = fmaf(wv, sh0s[0][j], a0);
      a1 = fmaf(wv, sh0s[1][j], a1);
    }
    a0 += __shfl_xor(a0, 1); a0 += __shfl_xor(a0, 2);
    a1 += __shfl_xor(a1, 1); a1 += __shfl_xor(a1, 2);
    if (pt == 0) { b1e[o] = b1[o] + a0; b1e[64 + o] = b1[o] + a1; }
  }
}

// ---------------- layer 2 (3-pass MFMA, atomic BN stats) ----------------
__global__ __launch_bounds__(256) void k_layer2(
    const u16* __restrict__ h1h, const u16* __restrict__ h1l,
    const u16* __restrict__ w1p, const float* __restrict__ b1e,
    float* __restrict__ h2, float* __restrict__ sums)
{
  const int tid = threadIdx.x;
  const int w = tid >> 6, l = tid & 63;
  const int l15 = l & 15, l4 = l >> 4;
  const int blk = blockIdx.x;
  const int rowHalf = w & 1, colHalf = w >> 1;
  const int r0 = blk * 32 + 16 * rowHalf;
  const int c0 = 32 * colHalf;
  const int b = blk >> 8;
  const u16* arow_h = h1h + (size_t)(r0 + l15) * 128;
  const u16* arow_l = h1l + (size_t)(r0 + l15) * 128;

  f32x4 acc[2];
  acc[0] = (f32x4){0.f, 0.f, 0.f, 0.f};
  acc[1] = (f32x4){0.f, 0.f, 0.f, 0.f};

  #pragma unroll
  for (int ks = 0; ks < 4; ++ks) {
    bf16x8 ah = *(const bf16x8*)(arow_h + ks * 32 + l4 * 8);
    bf16x8 al_ = *(const bf16x8*)(arow_l + ks * 32 + l4 * 8);
    const u16* bb = w1p + ((size_t)(b * 2) * 16 + ks * 4 + l4) * 512;
    #pragma unroll
    for (int ct = 0; ct < 2; ++ct) {
      const int col = c0 + 16 * ct + l15;
      bf16x8 bh = *(const bf16x8*)(bb + col * 8);
      bf16x8 bl = *(const bf16x8*)(bb + 8192 + col * 8);
      acc[ct] = __builtin_amdgcn_mfma_f32_16x16x32_bf16(ah, bh, acc[ct], 0, 0, 0);
      acc[ct] = __builtin_amdgcn_mfma_f32_16x16x32_bf16(ah, bl, acc[ct], 0, 0, 0);
      acc[ct] = __builtin_amdgcn_mfma_f32_16x16x32_bf16(al_, bh, acc[ct], 0, 0, 0);
    }
  }

  #pragma unroll
  for (int ct = 0; ct < 2; ++ct) {
    const int col = c0 + 16 * ct + l15;
    const float bj = b1e[b * 64 + col];
    float s = 0.f, q = 0.f;
    #pragma unroll
    for (int r = 0; r < 4; ++r) {
      float v = tanh_fast(acc[ct][r] + bj);
      const int row = r0 + 4 * l4 + r;
      h2[(size_t)row * 64 + col] = v;
      s += v; q += v * v;
    }
    s += __shfl_xor(s, 16); s += __shfl_xor(s, 32);
    q += __shfl_xor(q, 16); q += __shfl_xor(q, 32);
    if (l < 16) {
      AADD(&sums[512 + b * 64 + col], s);
      AADD(&sums[640 + b * 64 + col], q);
    }
  }
}

// ---------------- BN2 + single-bf16 round (q + permuted/padded k) ----------------
__global__ __launch_bounds__(256) void k_bn2(
    const float* __restrict__ h2, const float* __restrict__ sums,
    const float* __restrict__ g1, const float* __restrict__ bt1,
    const int* __restrict__ pidx,
    u16* __restrict__ qb, float* __restrict__ qn2,
    u16* __restrict__ kb, float* __restrict__ kn2)
{
  const int tid = threadIdx.x;
  const int r = tid >> 6, o = tid & 63;
  const bool isq = (blockIdx.x < 2048);
  const int b = isq ? 0 : 1;
  float s = sums[512 + b * 64 + o], q = sums[640 + b * 64 + o];
  float m = s * (1.f / 8192.f);
  float v = q * (1.f / 8192.f) - m * m;
  float sc = g1[o] * rsqrtf(v + EPSBN);
  float sh = bt1[o] - m * sc;
  if (isq) {
    const int row = blockIdx.x * 4 + r;
    float vv = sc * h2[(size_t)row * 64 + o] + sh;
    qb[(size_t)row * 64 + o] = f2bf(vv);
    float sq = vv * vv;
    #pragma unroll
    for (int off = 32; off; off >>= 1) sq += __shfl_xor(sq, off);
    if (o == 0) qn2[row] = SCL * sq;
  } else {
    const int row = (blockIdx.x - 2048) * 4 + r;   // 0..8831
    const int src = pidx[row];
    float vv = 0.f;
    if (src >= 0) vv = sc * h2[(size_t)(NROWS + src) * 64 + o] + sh;
    kb[(size_t)row * 64 + o] = f2bf(vv);
    float sq = vv * vv;
    #pragma unroll
    for (int off = 32; off; off >>= 1) sq += __shfl_xor(sq, off);
    if (o == 0) kn2[row] = (src >= 0) ? SCL * sq : 1e30f;
  }
}

// -------- cdist: 1-pass bf16, 128-col super-tiles, dbuf, fused finalize --------
__global__ __launch_bounds__(256, 4) void k_dist(
    const u16* __restrict__ qb, const float* __restrict__ qn2,
    const u16* __restrict__ kb, const float* __restrict__ kn2,
    const int* __restrict__ tcls, float* __restrict__ part,
    int* __restrict__ cntd, float* __restrict__ out)
{
  __shared__ u16 bs[2][8192];                       // 2 x 16 KB (128 cols x 64 k)
  __shared__ float cls_lds[2 * (NCLS + 1) * 64];
  __shared__ int lastflag;
  const int tid = threadIdx.x;
  const int w = tid >> 6, l = tid & 63;
  const int n0 = blockIdx.x * 64;
  const int g = blockIdx.y;
  const int t0 = (g * NST) / GY, t1 = ((g + 1) * NST) / GY;   // super-tile units

  for (int i = tid; i < 2 * (NCLS + 1) * 64; i += 256) cls_lds[i] = 0.f;

  const int lh = l >> 5;
  const int rb = w >> 1, ch = w & 1;
  const int arow = n0 + 32 * rb + (l & 31);
  bf16x8 aB[4];
  #pragma unroll
  for (int j = 0; j < 4; ++j)
    aB[j] = *(const bf16x8*)(qb + (size_t)arow * 64 + j * 16 + 8 * lh);
  float qnr[16];
  #pragma unroll
  for (int g4 = 0; g4 < 4; ++g4) {
    f32x4 qv = *(const f32x4*)(qn2 + n0 + 32 * rb + 8 * g4 + 4 * lh);
    qnr[4*g4+0] = qv[0]; qnr[4*g4+1] = qv[1]; qnr[4*g4+2] = qv[2]; qnr[4*g4+3] = qv[3];
  }

  // staging: wave w covers cols [32w, 32w+32); lane l of instr q:
  //   col = 32w + 8q + (l>>3), slot = l&7, content k-range = slot ^ (col&7) = (l&7)^(l>>3)
  int soff[4];
  #pragma unroll
  for (int q = 0; q < 4; ++q)
    soff[q] = (32 * w + 8 * q + (l >> 3)) * 64 + ((l & 7) ^ (l >> 3)) * 8;

  const int colc0 = 64 * ch + (l & 31);             // wave's first col-block

#define STAGE(TT, PB) do { const size_t tb_ = (size_t)(TT) * 8192; \
    u16* lb_ = &bs[PB][0] + w * 2048; \
    glds16(kb + tb_ + soff[0], lb_);        \
    glds16(kb + tb_ + soff[1], lb_ + 512);  \
    glds16(kb + tb_ + soff[2], lb_ + 1024); \
    glds16(kb + tb_ + soff[3], lb_ + 1536); } while (0)

#define FLUSH(CC) do { \
    _Pragma("unroll") for (int r = 0; r < 16; ++r) { \
      run[r] += __shfl_xor(run[r], 1);  run[r] += __shfl_xor(run[r], 2); \
      run[r] += __shfl_xor(run[r], 4);  run[r] += __shfl_xor(run[r], 8); \
      run[r] += __shfl_xor(run[r], 16); } \
    if ((l & 31) == 0) { \
      float* cl_ = cls_lds + ch * 704 + (CC) * 64 + 32 * rb + 4 * lh; \
      _Pragma("unroll") for (int r = 0; r < 16; ++r) cl_[(r & 3) + 8 * (r >> 2)] += run[r]; } \
    _Pragma("unroll") for (int r = 0; r < 16; ++r) run[r] = 0.f; } while (0)

  STAGE(t0, 0);

  float run[16];
  #pragma unroll
  for (int r = 0; r < 16; ++r) run[r] = 0.f;
  int ccur = tcls[2 * t0 + ch];
  int p = 0;

  for (int t = t0; t < t1; ++t) {
    __syncthreads();                       // buf[p] staged (drains vmcnt)
    if (t + 1 < t1) STAGE(t + 1, p ^ 1);
    const int c = tcls[2 * t + ch];
    if (c != ccur) { FLUSH(ccur); ccur = c; }
    const float kv0 = kn2[t * 128 + colc0];
    const float kv1 = kn2[t * 128 + colc0 + 32];

    f32x16 acc0, acc1;
    #pragma unroll
    for (int r = 0; r < 16; ++r) { acc0[r] = 0.f; acc1[r] = 0.f; }
    const char* pb_ = (const char*)&bs[p][0];
    #pragma unroll
    for (int j = 0; j < 4; ++j) {
      const int r_ = 2 * j + lh;
      bf16x8 b0_ = *(const bf16x8*)(pb_ + colc0 * 128 + ((r_ ^ (colc0 & 7)) << 4));
      bf16x8 b1_ = *(const bf16x8*)(pb_ + (colc0 + 32) * 128 + ((r_ ^ ((colc0 + 32) & 7)) << 4));
      acc0 = __builtin_amdgcn_mfma_f32_32x32x16_bf16(aB[j], b0_, acc0, 0, 0, 0);
      acc1 = __builtin_amdgcn_mfma_f32_32x32x16_bf16(aB[j], b1_, acc1, 0, 0, 0);
    }
    #pragma unroll
    for (int r = 0; r < 16; ++r) {
      float d2 = fmaf(SCL2, acc0[r], qnr[r] + kv0);
      d2 = fmaxf(d2, 2.0813689e-12f);
      run[r] += __builtin_amdgcn_exp2f(-__builtin_amdgcn_sqrtf(d2));
      float e2 = fmaf(SCL2, acc1[r], qnr[r] + kv1);
      e2 = fmaxf(e2, 2.0813689e-12f);
      run[r] += __builtin_amdgcn_exp2f(-__builtin_amdgcn_sqrtf(e2));
    }
    p ^= 1;
  }
  FLUSH(ccur);
  __syncthreads();

  for (int i = tid; i < (NCLS + 1) * 64; i += 256) {
    const int c = i >> 6, rr = i & 63;
    part[((size_t)g * (NCLS + 1) + c) * NROWS + n0 + rr] = cls_lds[i] + cls_lds[704 + i];
  }

  // ---- last-arrival finalize for this n0 (replaces k_final launch) ----
  __syncthreads();                         // drain all part stores to L2
  if (tid == 0) {
    __threadfence();                       // release: write back XCD L2
    int old = __hip_atomic_fetch_add(&cntd[blockIdx.x], 1,
                                     __ATOMIC_ACQ_REL, __HIP_MEMORY_SCOPE_AGENT);
    lastflag = (old == GY - 1) ? 1 : 0;
    if (lastflag) __threadfence();         // acquire: invalidate stale caches
  }
  __syncthreads();
  if (lastflag && tid < 64) {
    const int n = n0 + tid;
    float sc[NCLS];
    #pragma unroll
    for (int c = 0; c < NCLS; ++c) sc[c] = 0.f;
    for (int gg = 0; gg < GY; ++gg) {
      #pragma unroll
      for (int c = 0; c < NCLS; ++c)
        sc[c] += part[((size_t)gg * (NCLS + 1) + c) * NROWS + n];
    }
    float tot = 0.f;
    #pragma unroll
    for (int c = 0; c < NCLS; ++c) tot += sc[c];
    const float inv = 1.f / tot;
    #pragma unroll
    for (int c = 0; c < NCLS; ++c)
      out[(size_t)n * NCLS + c] = fminf(fmaxf(sc[c] * inv, 0.f), 1.f);
  }
#undef STAGE
#undef FLUSH
}

extern "C" void kernel_launch(void* const* d_in, const int* in_sizes, int n_in,
                              void* d_out, int out_size, void* d_ws, size_t ws_size,
                              hipStream_t stream) {
  const float* x   = (const float*)d_in[0];
  const float* xn  = (const float*)d_in[1];
  const int*   yn  = (const int*)d_in[2];
  const float* W0  = (const float*)d_in[3];
  const float* b0  = (const float*)d_in[4];
  const float* g0  = (const float*)d_in[5];
  const float* bt0 = (const float*)d_in[6];
  const float* W1  = (const float*)d_in[7];
  const float* b1  = (const float*)d_in[8];
  const float* g1  = (const float*)d_in[9];
  const float* bt1 = (const float*)d_in[10];
  float* out = (float*)d_out;
  float* ws  = (float*)d_ws;

  u16*   w0pp = (u16*)(ws + OFF_W0P);
  u16*   h1hp = (u16*)(ws + OFF_H1H);
  u16*   h1lp = (u16*)(ws + OFF_H1L);
  float* sumsp= ws + OFF_SUM;
  int*   cnt1p= (int*)(ws + OFF_CNT);
  int*   cntdp= cnt1p + 1;
  u16*   w1pp = (u16*)(ws + OFF_W1P);
  float* b1ep = ws + OFF_B1E;
  float* h2p  = ws + OFF_H2;
  int*   pidxp= (int*)(ws + OFF_PIDX);
  int*   tclsp= (int*)(ws + OFF_TCLS);
  u16*   qbp  = (u16*)(ws + OFF_QB);
  float* qn2p = ws + OFF_QN2;
  u16*   kbp  = (u16*)(ws + OFF_KB);
  float* kn2p = ws + OFF_KN2;
  float* partp= ws + OFF_PART;

  hipMemsetAsync((void*)sumsp, 0, (768 + 160) * sizeof(float), stream);
  k_prep<<<129, 256, 0, stream>>>(W0, yn, w0pp, pidxp, tclsp);
  k_layer1<<<512, 256, 0, stream>>>(x, xn, w0pp, b0, W1, b1, g0, bt0,
                                    h1hp, h1lp, sumsp, w1pp, b1ep, cnt1p);
  k_layer2<<<512, 256, 0, stream>>>(h1hp, h1lp, w1pp, b1ep, h2p, sumsp);
  k_bn2<<<2048 + MPAD / 4, 256, 0, stream>>>(h2p, sumsp, g1, bt1, pidxp,
                                             qbp, qn2p, kbp, kn2p);
  k_dist<<<dim3(128, GY), 256, 0, stream>>>(qbp, qn2p, kbp, kn2p, tclsp,
                                            partp, cntdp, out);
}

// Round 9
// 161.623 us; speedup vs baseline: 4.2981x; 1.1424x over previous
//
#include <hip/hip_runtime.h>
#include <math.h>

#define EPSBN 1e-5f
#define AADD(p, v) __hip_atomic_fetch_add((p), (v), __ATOMIC_RELAXED, __HIP_MEMORY_SCOPE_AGENT)

typedef unsigned short u16;
typedef short bf16x8 __attribute__((ext_vector_type(8)));
typedef float f32x4 __attribute__((ext_vector_type(4)));
typedef float f32x16 __attribute__((ext_vector_type(16)));

constexpr int NROWS = 8192;
constexpr int NCLS = 10;
constexpr int MPAD = 8832;        // 138 tiles of 64
constexpr int NT_PAD = 138;
constexpr int GY = 8;
constexpr float SCL  = 2.0813689810056077f;   // (log2 e)^2
constexpr float SCL2 = -4.1627379620112154f;  // -2*(log2 e)^2

// workspace offsets (floats)
constexpr size_t OFF_W0P = 0;                      // u16[65536]
constexpr size_t OFF_H1H = 32768;                  // u16[16384*128] = 1048576 f
constexpr size_t OFF_H1L = OFF_H1H + 1048576;
constexpr size_t OFF_SUM = OFF_H1L + 1048576;      // 768 f (zeroed by memset)
constexpr size_t OFF_CNT = OFF_SUM + 768;          // 160 ints (zeroed)
constexpr size_t OFF_W1P = OFF_CNT + 160;          // u16[32768]
constexpr size_t OFF_B1E = OFF_W1P + 16384;        // 128 f
constexpr size_t OFF_H2  = OFF_B1E + 128;          // 16384*64 f
constexpr size_t OFF_PIDX = OFF_H2 + 1048576;      // int[8832]
constexpr size_t OFF_TCLS = OFF_PIDX + MPAD;       // int[144]
// overlays over h1 (dead after layer2)
constexpr size_t OFF_QB  = OFF_H1H;                // u16[8192*64]  = 262144 f
constexpr size_t OFF_KB  = OFF_QB + 262144;        // u16[8832*64]  = 282624 f
constexpr size_t OFF_QN2 = OFF_KB + 282624;        // 8192 f
constexpr size_t OFF_KN2 = OFF_QN2 + NROWS;        // 8832 f
// part over h2 (dead after bn2): 8*11*8192 = 720896 <= 1048576
constexpr size_t OFF_PART = OFF_H2;

__device__ inline u16 f2bf(float f) {
  unsigned u = __float_as_uint(f);
  unsigned r = (u + 0x7fffu + ((u >> 16) & 1u)) >> 16;
  return (u16)r;
}
__device__ inline float bf2f(u16 h) { return __uint_as_float(((unsigned)h) << 16); }

__device__ inline float tanh_fast(float x) {
  float e = __builtin_amdgcn_exp2f(x * 2.88539008f);
  return 1.f - 2.f * __builtin_amdgcn_rcpf(e + 1.f);
}

__device__ inline void glds16(const u16* g, u16* l) {
  __builtin_amdgcn_global_load_lds(
      (const __attribute__((address_space(1))) unsigned int*)g,
      (__attribute__((address_space(3))) unsigned int*)l, 16, 0, 0);
}

// ---------------- prep: W0 pack (blocks 0-127) + class sort (block 128) ----------
__global__ __launch_bounds__(256) void k_prep(
    const float* __restrict__ w0, const int* __restrict__ yn,
    u16* __restrict__ w0p, int* __restrict__ pidx, int* __restrict__ tcls)
{
  if (blockIdx.x < 128) {
    int idx = blockIdx.x * 256 + threadIdx.x;
    int t = idx & 255;
    float v = w0[idx];
    u16 hi = f2bf(v);
    u16 lo = f2bf(v - bf2f(hi));
    int j = idx >> 8;
    w0p[(t >> 3) * 1024 + j * 8 + (t & 7)] = hi;
    w0p[32768 + (t >> 3) * 1024 + j * 8 + (t & 7)] = lo;
    return;
  }
  __shared__ int cnt[256][NCLS];
  __shared__ int wtot[4][NCLS];
  __shared__ int pstart[NCLS + 1];
  const int t = threadIdx.x;
  const int lane = t & 63, wv = t >> 6;
  #pragma unroll
  for (int c = 0; c < NCLS; ++c) cnt[t][c] = 0;
  for (int i = t; i < MPAD; i += 256) pidx[i] = -1;
  for (int i = t; i < NROWS; i += 256) cnt[t][yn[i]]++;
  __syncthreads();
  #pragma unroll
  for (int c = 0; c < NCLS; ++c) {
    int x = cnt[t][c];
    int inc = x;
    #pragma unroll
    for (int d = 1; d < 64; d <<= 1) { int y = __shfl_up(inc, d); if (lane >= d) inc += y; }
    if (lane == 63) wtot[wv][c] = inc;
    cnt[t][c] = inc - x;
  }
  __syncthreads();
  if (t == 0) {
    int run = 0;
    #pragma unroll
    for (int c = 0; c < NCLS; ++c) {
      int tot = wtot[0][c] + wtot[1][c] + wtot[2][c] + wtot[3][c];
      pstart[c] = run;
      int ntile = (tot + 63) >> 6;
      for (int tt = 0; tt < ntile; ++tt) tcls[(run >> 6) + tt] = c;
      run += ntile << 6;
    }
    pstart[NCLS] = run;
    for (int tt = run >> 6; tt < NT_PAD; ++tt) tcls[tt] = NCLS;
  }
  __syncthreads();
  #pragma unroll
  for (int c = 0; c < NCLS; ++c) {
    int add = pstart[c];
    for (int w2 = 0; w2 < 4; ++w2) if (w2 < wv) add += wtot[w2][c];
    cnt[t][c] += add;
  }
  __syncthreads();
  for (int i = t; i < NROWS; i += 256) {
    int c = yn[i];
    pidx[cnt[t][c]++] = i;
  }
}

// ---------------- layer 1 (3-pass MFMA) + BN1-fold tail in last block ------------
__global__ __launch_bounds__(256) void k_layer1(
    const float* __restrict__ x, const float* __restrict__ xn,
    const u16* __restrict__ w0p, const float* __restrict__ b0,
    const float* __restrict__ W1, const float* __restrict__ b1,
    const float* __restrict__ g0, const float* __restrict__ bt0,
    u16* __restrict__ h1h, u16* __restrict__ h1l, float* __restrict__ sums,
    u16* __restrict__ w1p, float* __restrict__ b1e, int* __restrict__ cnt1)
{
  const int tid = threadIdx.x;
  const int w = tid >> 6, l = tid & 63;
  const int l15 = l & 15, l4 = l >> 4;
  const int blk = blockIdx.x;                 // 512
  const int rowHalf = w & 1, colHalf = w >> 1;
  const int r0 = blk * 32 + 16 * rowHalf;
  const int c0 = 64 * colHalf;
  const int b = (blk < 256) ? 0 : 1;
  const float* src = (blk < 256) ? (x + (size_t)blk * 32 * 256)
                                 : (xn + (size_t)(blk - 256) * 32 * 256);
  const float* xrow = src + (size_t)(16 * rowHalf + l15) * 256;

  f32x4 acc[4];
  #pragma unroll
  for (int ct = 0; ct < 4; ++ct) acc[ct] = (f32x4){0.f, 0.f, 0.f, 0.f};

  #pragma unroll
  for (int ks = 0; ks < 8; ++ks) {
    const float* xp = xrow + ks * 32 + l4 * 8;
    f32x4 a0 = *(const f32x4*)xp;
    f32x4 a1 = *(const f32x4*)(xp + 4);
    bf16x8 ah, al_;
    #pragma unroll
    for (int i = 0; i < 4; ++i) {
      u16 h = f2bf(a0[i]); ah[i] = (short)h; al_[i] = (short)f2bf(a0[i] - bf2f(h));
    }
    #pragma unroll
    for (int i = 0; i < 4; ++i) {
      u16 h = f2bf(a1[i]); ah[4 + i] = (short)h; al_[4 + i] = (short)f2bf(a1[i] - bf2f(h));
    }
    const u16* bbase = w0p + (size_t)(ks * 4 + l4) * 1024;
    #pragma unroll
    for (int ct = 0; ct < 4; ++ct) {
      const int col = c0 + 16 * ct + l15;
      bf16x8 bh = *(const bf16x8*)(bbase + col * 8);
      bf16x8 bl = *(const bf16x8*)(bbase + 32768 + col * 8);
      acc[ct] = __builtin_amdgcn_mfma_f32_16x16x32_bf16(ah, bh, acc[ct], 0, 0, 0);
      acc[ct] = __builtin_amdgcn_mfma_f32_16x16x32_bf16(ah, bl, acc[ct], 0, 0, 0);
      acc[ct] = __builtin_amdgcn_mfma_f32_16x16x32_bf16(al_, bh, acc[ct], 0, 0, 0);
    }
  }

  #pragma unroll
  for (int ct = 0; ct < 4; ++ct) {
    const int col = c0 + 16 * ct + l15;
    const float bj = b0[col];
    float s = 0.f, q = 0.f;
    #pragma unroll
    for (int r = 0; r < 4; ++r) {
      float v = tanh_fast(acc[ct][r] + bj);
      const int row = r0 + 4 * l4 + r;
      u16 hi = f2bf(v);
      h1h[(size_t)row * 128 + col] = hi;
      h1l[(size_t)row * 128 + col] = f2bf(v - bf2f(hi));
      s += v; q += v * v;
    }
    s += __shfl_xor(s, 16); s += __shfl_xor(s, 32);
    q += __shfl_xor(q, 16); q += __shfl_xor(q, 32);
    if (l < 16) {
      AADD(&sums[b * 128 + col], s);
      AADD(&sums[256 + b * 128 + col], q);
    }
  }

  // ---- last-block tail: fold BN1 into W1 ----
  __shared__ int lastflag;
  __syncthreads();
  if (tid == 0) {
    int old = __hip_atomic_fetch_add(cnt1, 1, __ATOMIC_ACQ_REL, __HIP_MEMORY_SCOPE_AGENT);
    lastflag = (old == 511) ? 1 : 0;
  }
  __syncthreads();
  if (!lastflag) return;

  __shared__ float sc0s[2][128], sh0s[2][128];
  {
    int bb = tid >> 7, j = tid & 127;
    float s = __hip_atomic_load(&sums[bb * 128 + j], __ATOMIC_RELAXED, __HIP_MEMORY_SCOPE_AGENT);
    float q = __hip_atomic_load(&sums[256 + bb * 128 + j], __ATOMIC_RELAXED, __HIP_MEMORY_SCOPE_AGENT);
    float m = s * (1.f / 8192.f);
    float v = q * (1.f / 8192.f) - m * m;
    float sc = g0[j] * rsqrtf(v + EPSBN);
    sc0s[bb][j] = sc;
    sh0s[bb][j] = bt0[j] - m * sc;
  }
  __syncthreads();
  {
    const int o = tid >> 2, pt = tid & 3;
    float a0 = 0.f, a1 = 0.f;
    for (int jj = 0; jj < 32; ++jj) {
      int j = pt * 32 + jj;
      float wv = W1[o * 128 + j];
      float w0_ = wv * sc0s[0][j];
      float w1_ = wv * sc0s[1][j];
      u16 h0 = f2bf(w0_), h1_ = f2bf(w1_);
      w1p[((size_t)(j >> 3)) * 512 + o * 8 + (j & 7)] = h0;
      w1p[((size_t)(16 + (j >> 3))) * 512 + o * 8 + (j & 7)] = f2bf(w0_ - bf2f(h0));
      w1p[((size_t)(32 + (j >> 3))) * 512 + o * 8 + (j & 7)] = h1_;
      w1p[((size_t)(48 + (j >> 3))) * 512 + o * 8 + (j & 7)] = f2bf(w1_ - bf2f(h1_));
      a0 = fmaf(wv, sh0s[0][j], a0);
      a1 = fmaf(wv, sh0s[1][j], a1);
    }
    a0 += __shfl_xor(a0, 1); a0 += __shfl_xor(a0, 2);
    a1 += __shfl_xor(a1, 1); a1 += __shfl_xor(a1, 2);
    if (pt == 0) { b1e[o] = b1[o] + a0; b1e[64 + o] = b1[o] + a1; }
  }
}

// ---------------- layer 2 (3-pass MFMA, atomic BN stats) ----------------
__global__ __launch_bounds__(256) void k_layer2(
    const u16* __restrict__ h1h, const u16* __restrict__ h1l,
    const u16* __restrict__ w1p, const float* __restrict__ b1e,
    float* __restrict__ h2, float* __restrict__ sums)
{
  const int tid = threadIdx.x;
  const int w = tid >> 6, l = tid & 63;
  const int l15 = l & 15, l4 = l >> 4;
  const int blk = blockIdx.x;
  const int rowHalf = w & 1, colHalf = w >> 1;
  const int r0 = blk * 32 + 16 * rowHalf;
  const int c0 = 32 * colHalf;
  const int b = blk >> 8;
  const u16* arow_h = h1h + (size_t)(r0 + l15) * 128;
  const u16* arow_l = h1l + (size_t)(r0 + l15) * 128;

  f32x4 acc[2];
  acc[0] = (f32x4){0.f, 0.f, 0.f, 0.f};
  acc[1] = (f32x4){0.f, 0.f, 0.f, 0.f};

  #pragma unroll
  for (int ks = 0; ks < 4; ++ks) {
    bf16x8 ah = *(const bf16x8*)(arow_h + ks * 32 + l4 * 8);
    bf16x8 al_ = *(const bf16x8*)(arow_l + ks * 32 + l4 * 8);
    const u16* bb = w1p + ((size_t)(b * 2) * 16 + ks * 4 + l4) * 512;
    #pragma unroll
    for (int ct = 0; ct < 2; ++ct) {
      const int col = c0 + 16 * ct + l15;
      bf16x8 bh = *(const bf16x8*)(bb + col * 8);
      bf16x8 bl = *(const bf16x8*)(bb + 8192 + col * 8);
      acc[ct] = __builtin_amdgcn_mfma_f32_16x16x32_bf16(ah, bh, acc[ct], 0, 0, 0);
      acc[ct] = __builtin_amdgcn_mfma_f32_16x16x32_bf16(ah, bl, acc[ct], 0, 0, 0);
      acc[ct] = __builtin_amdgcn_mfma_f32_16x16x32_bf16(al_, bh, acc[ct], 0, 0, 0);
    }
  }

  #pragma unroll
  for (int ct = 0; ct < 2; ++ct) {
    const int col = c0 + 16 * ct + l15;
    const float bj = b1e[b * 64 + col];
    float s = 0.f, q = 0.f;
    #pragma unroll
    for (int r = 0; r < 4; ++r) {
      float v = tanh_fast(acc[ct][r] + bj);
      const int row = r0 + 4 * l4 + r;
      h2[(size_t)row * 64 + col] = v;
      s += v; q += v * v;
    }
    s += __shfl_xor(s, 16); s += __shfl_xor(s, 32);
    q += __shfl_xor(q, 16); q += __shfl_xor(q, 32);
    if (l < 16) {
      AADD(&sums[512 + b * 64 + col], s);
      AADD(&sums[640 + b * 64 + col], q);
    }
  }
}

// ---------------- BN2 + single-bf16 round (q + permuted/padded k) ----------------
__global__ __launch_bounds__(256) void k_bn2(
    const float* __restrict__ h2, const float* __restrict__ sums,
    const float* __restrict__ g1, const float* __restrict__ bt1,
    const int* __restrict__ pidx,
    u16* __restrict__ qb, float* __restrict__ qn2,
    u16* __restrict__ kb, float* __restrict__ kn2)
{
  const int tid = threadIdx.x;
  const int r = tid >> 6, o = tid & 63;
  const bool isq = (blockIdx.x < 2048);
  const int b = isq ? 0 : 1;
  float s = sums[512 + b * 64 + o], q = sums[640 + b * 64 + o];
  float m = s * (1.f / 8192.f);
  float v = q * (1.f / 8192.f) - m * m;
  float sc = g1[o] * rsqrtf(v + EPSBN);
  float sh = bt1[o] - m * sc;
  if (isq) {
    const int row = blockIdx.x * 4 + r;
    float vv = sc * h2[(size_t)row * 64 + o] + sh;
    qb[(size_t)row * 64 + o] = f2bf(vv);
    float sq = vv * vv;
    #pragma unroll
    for (int off = 32; off; off >>= 1) sq += __shfl_xor(sq, off);
    if (o == 0) qn2[row] = SCL * sq;
  } else {
    const int row = (blockIdx.x - 2048) * 4 + r;   // 0..8831
    const int src = pidx[row];
    float vv = 0.f;
    if (src >= 0) vv = sc * h2[(size_t)(NROWS + src) * 64 + o] + sh;
    kb[(size_t)row * 64 + o] = f2bf(vv);
    float sq = vv * vv;
    #pragma unroll
    for (int off = 32; off; off >>= 1) sq += __shfl_xor(sq, off);
    if (o == 0) kn2[row] = (src >= 0) ? SCL * sq : 1e30f;
  }
}

// -------- cdist: 1-pass bf16, 64-col tiles, TRIPLE buffer + counted vmcnt --------
__global__ __launch_bounds__(256, 4) void k_dist(
    const u16* __restrict__ qb, const float* __restrict__ qn2,
    const u16* __restrict__ kb, const float* __restrict__ kn2,
    const int* __restrict__ tcls, float* __restrict__ part)
{
  __shared__ u16 bs[3][4096];                       // 3 x 8 KB
  __shared__ float cls_lds[2 * (NCLS + 1) * 64];
  const int tid = threadIdx.x;
  const int w = tid >> 6, l = tid & 63;
  const int n0 = blockIdx.x * 64;
  const int g = blockIdx.y;
  const int t0 = (g * NT_PAD) / GY, t1 = ((g + 1) * NT_PAD) / GY;

  for (int i = tid; i < 2 * (NCLS + 1) * 64; i += 256) cls_lds[i] = 0.f;

  const int lh = l >> 5;
  const int rb = w >> 1, ch = w & 1;
  const int arow = n0 + 32 * rb + (l & 31);
  bf16x8 aB[4];
  #pragma unroll
  for (int j = 0; j < 4; ++j)
    aB[j] = *(const bf16x8*)(qb + (size_t)arow * 64 + j * 16 + 8 * lh);
  float qnr[16];
  #pragma unroll
  for (int g4 = 0; g4 < 4; ++g4) {
    f32x4 qv = *(const f32x4*)(qn2 + n0 + 32 * rb + 8 * g4 + 4 * lh);
    qnr[4*g4+0] = qv[0]; qnr[4*g4+1] = qv[1]; qnr[4*g4+2] = qv[2]; qnr[4*g4+3] = qv[3];
  }

  // staging: 2 glds/wave; instr q: col = 16w + 8q + (l>>3), src chunk = (l&7)^(l>>3)
  // LDS content invariant: {col c, chunk k8} at byte c*128 + ((k8 ^ (c&7))<<4)
  int soff[2];
  #pragma unroll
  for (int q = 0; q < 2; ++q)
    soff[q] = (16 * w + 8 * q + (l >> 3)) * 64 + ((l & 7) ^ (l >> 3)) * 8;   // u16 units

  const int colL = 32 * ch + (l & 31);
  const int c7 = colL & 7;

#define STAGE(TT, PB) do { const u16* gp_ = kb + (size_t)(TT) * 4096; \
    u16* lb_ = &bs[PB][0] + w * 1024; \
    glds16(gp_ + soff[0], lb_); \
    glds16(gp_ + soff[1], lb_ + 512); } while (0)

#define FLUSH(CC) do { \
    _Pragma("unroll") for (int r = 0; r < 16; ++r) { \
      run[r] += __shfl_xor(run[r], 1);  run[r] += __shfl_xor(run[r], 2); \
      run[r] += __shfl_xor(run[r], 4);  run[r] += __shfl_xor(run[r], 8); \
      run[r] += __shfl_xor(run[r], 16); } \
    if ((l & 31) == 0) { \
      float* cl_ = cls_lds + ch * 704 + (CC) * 64 + 32 * rb + 4 * lh; \
      _Pragma("unroll") for (int r = 0; r < 16; ++r) cl_[(r & 3) + 8 * (r >> 2)] += run[r]; } \
    _Pragma("unroll") for (int r = 0; r < 16; ++r) run[r] = 0.f; } while (0)

  STAGE(t0, 0);
  if (t0 + 1 < t1) STAGE(t0 + 1, 1);

  float run[16];
  #pragma unroll
  for (int r = 0; r < 16; ++r) run[r] = 0.f;
  int ccur = tcls[t0];
  int p = 0;

  for (int t = t0; t < t1; ++t) {
    // counted-vmcnt barrier: only stage(t) must be complete; stage(t+1)'s
    // 2 glds may stay in flight (never drain to 0 mid-loop — T4).
    if (t + 1 < t1) { asm volatile("s_waitcnt vmcnt(2)" ::: "memory"); }
    else            { asm volatile("s_waitcnt vmcnt(0)" ::: "memory"); }
    __builtin_amdgcn_s_barrier();
    asm volatile("" ::: "memory");

    if (t + 2 < t1) { int pb2 = p + 2; if (pb2 >= 3) pb2 -= 3; STAGE(t + 2, pb2); }

    const int c = tcls[t];
    if (c != ccur) { FLUSH(ccur); ccur = c; }
    const float kv = kn2[t * 64 + colL];

    f32x16 acc0, acc1;
    #pragma unroll
    for (int r = 0; r < 16; ++r) { acc0[r] = 0.f; acc1[r] = 0.f; }
    const char* pb_ = (const char*)&bs[p][0] + colL * 128;
    {
      bf16x8 b0_ = *(const bf16x8*)(pb_ + (((0 + lh) ^ c7) << 4));
      bf16x8 b1_ = *(const bf16x8*)(pb_ + (((2 + lh) ^ c7) << 4));
      bf16x8 b2_ = *(const bf16x8*)(pb_ + (((4 + lh) ^ c7) << 4));
      bf16x8 b3_ = *(const bf16x8*)(pb_ + (((6 + lh) ^ c7) << 4));
      acc0 = __builtin_amdgcn_mfma_f32_32x32x16_bf16(aB[0], b0_, acc0, 0, 0, 0);
      acc1 = __builtin_amdgcn_mfma_f32_32x32x16_bf16(aB[1], b1_, acc1, 0, 0, 0);
      acc0 = __builtin_amdgcn_mfma_f32_32x32x16_bf16(aB[2], b2_, acc0, 0, 0, 0);
      acc1 = __builtin_amdgcn_mfma_f32_32x32x16_bf16(aB[3], b3_, acc1, 0, 0, 0);
    }
    #pragma unroll
    for (int r = 0; r < 16; ++r) {
      float d2 = fmaf(SCL2, acc0[r] + acc1[r], qnr[r] + kv);
      d2 = fmaxf(d2, 2.0813689e-12f);
      run[r] += __builtin_amdgcn_exp2f(-__builtin_amdgcn_sqrtf(d2));
    }
    p = (p == 2) ? 0 : p + 1;
  }
  FLUSH(ccur);
  __syncthreads();

  for (int i = tid; i < (NCLS + 1) * 64; i += 256) {
    const int c = i >> 6, rr = i & 63;
    part[((size_t)g * (NCLS + 1) + c) * NROWS + n0 + rr] = cls_lds[i] + cls_lds[704 + i];
  }
#undef STAGE
#undef FLUSH
}

// ---- finalize ----
__global__ __launch_bounds__(256) void k_final(const float* __restrict__ part,
                                               float* __restrict__ out)
{
  const int n = blockIdx.x * 256 + threadIdx.x;
  float sc[NCLS];
  #pragma unroll
  for (int c = 0; c < NCLS; ++c) sc[c] = 0.f;
  for (int g = 0; g < GY; ++g) {
    #pragma unroll
    for (int c = 0; c < NCLS; ++c)
      sc[c] += part[((size_t)g * (NCLS + 1) + c) * NROWS + n];
  }
  float tot = 0.f;
  #pragma unroll
  for (int c = 0; c < NCLS; ++c) tot += sc[c];
  const float inv = 1.f / tot;
  #pragma unroll
  for (int c = 0; c < NCLS; ++c)
    out[(size_t)n * NCLS + c] = fminf(fmaxf(sc[c] * inv, 0.f), 1.f);
}

extern "C" void kernel_launch(void* const* d_in, const int* in_sizes, int n_in,
                              void* d_out, int out_size, void* d_ws, size_t ws_size,
                              hipStream_t stream) {
  const float* x   = (const float*)d_in[0];
  const float* xn  = (const float*)d_in[1];
  const int*   yn  = (const int*)d_in[2];
  const float* W0  = (const float*)d_in[3];
  const float* b0  = (const float*)d_in[4];
  const float* g0  = (const float*)d_in[5];
  const float* bt0 = (const float*)d_in[6];
  const float* W1  = (const float*)d_in[7];
  const float* b1  = (const float*)d_in[8];
  const float* g1  = (const float*)d_in[9];
  const float* bt1 = (const float*)d_in[10];
  float* out = (float*)d_out;
  float* ws  = (float*)d_ws;

  u16*   w0pp = (u16*)(ws + OFF_W0P);
  u16*   h1hp = (u16*)(ws + OFF_H1H);
  u16*   h1lp = (u16*)(ws + OFF_H1L);
  float* sumsp= ws + OFF_SUM;
  int*   cnt1p= (int*)(ws + OFF_CNT);
  u16*   w1pp = (u16*)(ws + OFF_W1P);
  float* b1ep = ws + OFF_B1E;
  float* h2p  = ws + OFF_H2;
  int*   pidxp= (int*)(ws + OFF_PIDX);
  int*   tclsp= (int*)(ws + OFF_TCLS);
  u16*   qbp  = (u16*)(ws + OFF_QB);
  float* qn2p = ws + OFF_QN2;
  u16*   kbp  = (u16*)(ws + OFF_KB);
  float* kn2p = ws + OFF_KN2;
  float* partp= ws + OFF_PART;

  hipMemsetAsync((void*)sumsp, 0, (768 + 160) * sizeof(float), stream);
  k_prep<<<129, 256, 0, stream>>>(W0, yn, w0pp, pidxp, tclsp);
  k_layer1<<<512, 256, 0, stream>>>(x, xn, w0pp, b0, W1, b1, g0, bt0,
                                    h1hp, h1lp, sumsp, w1pp, b1ep, cnt1p);
  k_layer2<<<512, 256, 0, stream>>>(h1hp, h1lp, w1pp, b1ep, h2p, sumsp);
  k_bn2<<<2048 + MPAD / 4, 256, 0, stream>>>(h2p, sumsp, g1, bt1, pidxp,
                                             qbp, qn2p, kbp, kn2p);
  k_dist<<<dim3(128, GY), 256, 0, stream>>>(qbp, qn2p, kbp, kn2p, tclsp, partp);
  k_final<<<32, 256, 0, stream>>>(partp, out);
}

// Round 10
// 142.494 us; speedup vs baseline: 4.8751x; 1.1342x over previous
//
#include <hip/hip_runtime.h>
#include <math.h>

#define EPSBN 1e-5f
#define AADD(p, v) __hip_atomic_fetch_add((p), (v), __ATOMIC_RELAXED, __HIP_MEMORY_SCOPE_AGENT)

typedef unsigned short u16;
typedef short bf16x8 __attribute__((ext_vector_type(8)));
typedef float f32x4 __attribute__((ext_vector_type(4)));
typedef float f32x16 __attribute__((ext_vector_type(16)));

constexpr int NROWS = 8192;
constexpr int NCLS = 10;
constexpr int MPAD = 8832;        // 138 tiles of 64
constexpr int NT_PAD = 138;
constexpr int GY = 8;
constexpr float SCL  = 2.0813689810056077f;   // (log2 e)^2
constexpr float SCL2 = -4.1627379620112154f;  // -2*(log2 e)^2

// workspace offsets (floats)
constexpr size_t OFF_W0P = 0;                      // u16[65536]
constexpr size_t OFF_H1H = 32768;                  // u16[16384*128] = 1048576 f
constexpr size_t OFF_H1L = OFF_H1H + 1048576;
constexpr size_t OFF_SUM = OFF_H1L + 1048576;      // 768 f (zeroed by memset)
constexpr size_t OFF_CNT = OFF_SUM + 768;          // 160 ints (zeroed, spare)
constexpr size_t OFF_W1P = OFF_CNT + 160;          // u16[32768]
constexpr size_t OFF_B1E = OFF_W1P + 16384;        // 128 f
constexpr size_t OFF_H2  = OFF_B1E + 128;          // 16384*64 f
constexpr size_t OFF_PIDX = OFF_H2 + 1048576;      // int[8832]
constexpr size_t OFF_TCLS = OFF_PIDX + MPAD;       // int[144]
// overlays over h1 (dead after layer2)
constexpr size_t OFF_QB  = OFF_H1H;                // u16[8192*64]  = 262144 f
constexpr size_t OFF_KB  = OFF_QB + 262144;        // u16[8832*64]  = 282624 f
constexpr size_t OFF_QN2 = OFF_KB + 282624;        // 8192 f
constexpr size_t OFF_KN2 = OFF_QN2 + NROWS;        // 8832 f
// part over h2 (dead after bn2): 8*11*8192 = 720896 <= 1048576
constexpr size_t OFF_PART = OFF_H2;

__device__ inline u16 f2bf(float f) {
  unsigned u = __float_as_uint(f);
  unsigned r = (u + 0x7fffu + ((u >> 16) & 1u)) >> 16;
  return (u16)r;
}
__device__ inline float bf2f(u16 h) { return __uint_as_float(((unsigned)h) << 16); }

__device__ inline float tanh_fast(float x) {
  float e = __builtin_amdgcn_exp2f(x * 2.88539008f);
  return 1.f - 2.f * __builtin_amdgcn_rcpf(e + 1.f);
}

__device__ inline void glds16(const u16* g, u16* l) {
  __builtin_amdgcn_global_load_lds(
      (const __attribute__((address_space(1))) unsigned int*)g,
      (__attribute__((address_space(3))) unsigned int*)l, 16, 0, 0);
}

// ---------------- prep: W0 pack (blocks 0-127) + class sort (block 128) ----------
__global__ __launch_bounds__(256) void k_prep(
    const float* __restrict__ w0, const int* __restrict__ yn,
    u16* __restrict__ w0p, int* __restrict__ pidx, int* __restrict__ tcls)
{
  if (blockIdx.x < 128) {
    int idx = blockIdx.x * 256 + threadIdx.x;
    int t = idx & 255;
    float v = w0[idx];
    u16 hi = f2bf(v);
    u16 lo = f2bf(v - bf2f(hi));
    int j = idx >> 8;
    w0p[(t >> 3) * 1024 + j * 8 + (t & 7)] = hi;
    w0p[32768 + (t >> 3) * 1024 + j * 8 + (t & 7)] = lo;
    return;
  }
  __shared__ int cnt[256][NCLS];
  __shared__ int wtot[4][NCLS];
  __shared__ int pstart[NCLS + 1];
  const int t = threadIdx.x;
  const int lane = t & 63, wv = t >> 6;
  #pragma unroll
  for (int c = 0; c < NCLS; ++c) cnt[t][c] = 0;
  for (int i = t; i < MPAD; i += 256) pidx[i] = -1;
  for (int i = t; i < NROWS; i += 256) cnt[t][yn[i]]++;
  __syncthreads();
  #pragma unroll
  for (int c = 0; c < NCLS; ++c) {
    int x = cnt[t][c];
    int inc = x;
    #pragma unroll
    for (int d = 1; d < 64; d <<= 1) { int y = __shfl_up(inc, d); if (lane >= d) inc += y; }
    if (lane == 63) wtot[wv][c] = inc;
    cnt[t][c] = inc - x;
  }
  __syncthreads();
  if (t == 0) {
    int run = 0;
    #pragma unroll
    for (int c = 0; c < NCLS; ++c) {
      int tot = wtot[0][c] + wtot[1][c] + wtot[2][c] + wtot[3][c];
      pstart[c] = run;
      int ntile = (tot + 63) >> 6;
      for (int tt = 0; tt < ntile; ++tt) tcls[(run >> 6) + tt] = c;
      run += ntile << 6;
    }
    pstart[NCLS] = run;
    for (int tt = run >> 6; tt < NT_PAD; ++tt) tcls[tt] = NCLS;
  }
  __syncthreads();
  #pragma unroll
  for (int c = 0; c < NCLS; ++c) {
    int add = pstart[c];
    for (int w2 = 0; w2 < 4; ++w2) if (w2 < wv) add += wtot[w2][c];
    cnt[t][c] += add;
  }
  __syncthreads();
  for (int i = t; i < NROWS; i += 256) {
    int c = yn[i];
    pidx[cnt[t][c]++] = i;
  }
}

// ---------------- layer 1 (3-pass MFMA, relaxed atomic BN stats only) -----------
__global__ __launch_bounds__(256) void k_layer1(
    const float* __restrict__ x, const float* __restrict__ xn,
    const u16* __restrict__ w0p, const float* __restrict__ b0,
    u16* __restrict__ h1h, u16* __restrict__ h1l, float* __restrict__ sums)
{
  const int tid = threadIdx.x;
  const int w = tid >> 6, l = tid & 63;
  const int l15 = l & 15, l4 = l >> 4;
  const int blk = blockIdx.x;                 // 512
  const int rowHalf = w & 1, colHalf = w >> 1;
  const int r0 = blk * 32 + 16 * rowHalf;
  const int c0 = 64 * colHalf;
  const int b = (blk < 256) ? 0 : 1;
  const float* src = (blk < 256) ? (x + (size_t)blk * 32 * 256)
                                 : (xn + (size_t)(blk - 256) * 32 * 256);
  const float* xrow = src + (size_t)(16 * rowHalf + l15) * 256;

  f32x4 acc[4];
  #pragma unroll
  for (int ct = 0; ct < 4; ++ct) acc[ct] = (f32x4){0.f, 0.f, 0.f, 0.f};

  #pragma unroll
  for (int ks = 0; ks < 8; ++ks) {
    const float* xp = xrow + ks * 32 + l4 * 8;
    f32x4 a0 = *(const f32x4*)xp;
    f32x4 a1 = *(const f32x4*)(xp + 4);
    bf16x8 ah, al_;
    #pragma unroll
    for (int i = 0; i < 4; ++i) {
      u16 h = f2bf(a0[i]); ah[i] = (short)h; al_[i] = (short)f2bf(a0[i] - bf2f(h));
    }
    #pragma unroll
    for (int i = 0; i < 4; ++i) {
      u16 h = f2bf(a1[i]); ah[4 + i] = (short)h; al_[4 + i] = (short)f2bf(a1[i] - bf2f(h));
    }
    const u16* bbase = w0p + (size_t)(ks * 4 + l4) * 1024;
    #pragma unroll
    for (int ct = 0; ct < 4; ++ct) {
      const int col = c0 + 16 * ct + l15;
      bf16x8 bh = *(const bf16x8*)(bbase + col * 8);
      bf16x8 bl = *(const bf16x8*)(bbase + 32768 + col * 8);
      acc[ct] = __builtin_amdgcn_mfma_f32_16x16x32_bf16(ah, bh, acc[ct], 0, 0, 0);
      acc[ct] = __builtin_amdgcn_mfma_f32_16x16x32_bf16(ah, bl, acc[ct], 0, 0, 0);
      acc[ct] = __builtin_amdgcn_mfma_f32_16x16x32_bf16(al_, bh, acc[ct], 0, 0, 0);
    }
  }

  #pragma unroll
  for (int ct = 0; ct < 4; ++ct) {
    const int col = c0 + 16 * ct + l15;
    const float bj = b0[col];
    float s = 0.f, q = 0.f;
    #pragma unroll
    for (int r = 0; r < 4; ++r) {
      float v = tanh_fast(acc[ct][r] + bj);
      const int row = r0 + 4 * l4 + r;
      u16 hi = f2bf(v);
      h1h[(size_t)row * 128 + col] = hi;
      h1l[(size_t)row * 128 + col] = f2bf(v - bf2f(hi));
      s += v; q += v * v;
    }
    s += __shfl_xor(s, 16); s += __shfl_xor(s, 32);
    q += __shfl_xor(q, 16); q += __shfl_xor(q, 32);
    if (l < 16) {
      AADD(&sums[b * 128 + col], s);
      AADD(&sums[256 + b * 128 + col], q);
    }
  }
}

// ---- parallel fold: BN1 scale/shift from sums -> packed W1eff + eff bias ----
// (separate kernel: kernel boundary provides the ordering; NO acq/rel atomics)
__global__ __launch_bounds__(128) void k_foldp(
    const float* __restrict__ w1, const float* __restrict__ b1,
    const float* __restrict__ g0, const float* __restrict__ bt0,
    const float* __restrict__ sums, u16* __restrict__ w1p, float* __restrict__ b1e)
{
  const int o = blockIdx.x;          // 64
  const int j = threadIdx.x;         // 128
  __shared__ float red[2][2];
  const float w = w1[o * 128 + j];
  #pragma unroll
  for (int b = 0; b < 2; ++b) {
    float s = sums[b * 128 + j], q = sums[256 + b * 128 + j];
    float m = s * (1.f / 8192.f);
    float v = q * (1.f / 8192.f) - m * m;
    float sc = g0[j] * rsqrtf(v + EPSBN);
    float sh = bt0[j] - m * sc;
    float wsc = w * sc;
    u16 hi = f2bf(wsc);
    u16 lo = f2bf(wsc - bf2f(hi));
    w1p[((size_t)(b * 2 + 0) * 16 + (j >> 3)) * 512 + o * 8 + (j & 7)] = hi;
    w1p[((size_t)(b * 2 + 1) * 16 + (j >> 3)) * 512 + o * 8 + (j & 7)] = lo;
    float a = w * sh;
    #pragma unroll
    for (int off = 32; off; off >>= 1) a += __shfl_xor(a, off);
    if ((j & 63) == 0) red[j >> 6][b] = a;
  }
  __syncthreads();
  if (j < 2) b1e[j * 64 + o] = b1[o] + red[0][j] + red[1][j];
}

// ---------------- layer 2 (3-pass MFMA, atomic BN stats) ----------------
__global__ __launch_bounds__(256) void k_layer2(
    const u16* __restrict__ h1h, const u16* __restrict__ h1l,
    const u16* __restrict__ w1p, const float* __restrict__ b1e,
    float* __restrict__ h2, float* __restrict__ sums)
{
  const int tid = threadIdx.x;
  const int w = tid >> 6, l = tid & 63;
  const int l15 = l & 15, l4 = l >> 4;
  const int blk = blockIdx.x;
  const int rowHalf = w & 1, colHalf = w >> 1;
  const int r0 = blk * 32 + 16 * rowHalf;
  const int c0 = 32 * colHalf;
  const int b = blk >> 8;
  const u16* arow_h = h1h + (size_t)(r0 + l15) * 128;
  const u16* arow_l = h1l + (size_t)(r0 + l15) * 128;

  f32x4 acc[2];
  acc[0] = (f32x4){0.f, 0.f, 0.f, 0.f};
  acc[1] = (f32x4){0.f, 0.f, 0.f, 0.f};

  #pragma unroll
  for (int ks = 0; ks < 4; ++ks) {
    bf16x8 ah = *(const bf16x8*)(arow_h + ks * 32 + l4 * 8);
    bf16x8 al_ = *(const bf16x8*)(arow_l + ks * 32 + l4 * 8);
    const u16* bb = w1p + ((size_t)(b * 2) * 16 + ks * 4 + l4) * 512;
    #pragma unroll
    for (int ct = 0; ct < 2; ++ct) {
      const int col = c0 + 16 * ct + l15;
      bf16x8 bh = *(const bf16x8*)(bb + col * 8);
      bf16x8 bl = *(const bf16x8*)(bb + 8192 + col * 8);
      acc[ct] = __builtin_amdgcn_mfma_f32_16x16x32_bf16(ah, bh, acc[ct], 0, 0, 0);
      acc[ct] = __builtin_amdgcn_mfma_f32_16x16x32_bf16(ah, bl, acc[ct], 0, 0, 0);
      acc[ct] = __builtin_amdgcn_mfma_f32_16x16x32_bf16(al_, bh, acc[ct], 0, 0, 0);
    }
  }

  #pragma unroll
  for (int ct = 0; ct < 2; ++ct) {
    const int col = c0 + 16 * ct + l15;
    const float bj = b1e[b * 64 + col];
    float s = 0.f, q = 0.f;
    #pragma unroll
    for (int r = 0; r < 4; ++r) {
      float v = tanh_fast(acc[ct][r] + bj);
      const int row = r0 + 4 * l4 + r;
      h2[(size_t)row * 64 + col] = v;
      s += v; q += v * v;
    }
    s += __shfl_xor(s, 16); s += __shfl_xor(s, 32);
    q += __shfl_xor(q, 16); q += __shfl_xor(q, 32);
    if (l < 16) {
      AADD(&sums[512 + b * 64 + col], s);
      AADD(&sums[640 + b * 64 + col], q);
    }
  }
}

// ---------------- BN2 + single-bf16 round (q + permuted/padded k) ----------------
__global__ __launch_bounds__(256) void k_bn2(
    const float* __restrict__ h2, const float* __restrict__ sums,
    const float* __restrict__ g1, const float* __restrict__ bt1,
    const int* __restrict__ pidx,
    u16* __restrict__ qb, float* __restrict__ qn2,
    u16* __restrict__ kb, float* __restrict__ kn2)
{
  const int tid = threadIdx.x;
  const int r = tid >> 6, o = tid & 63;
  const bool isq = (blockIdx.x < 2048);
  const int b = isq ? 0 : 1;
  float s = sums[512 + b * 64 + o], q = sums[640 + b * 64 + o];
  float m = s * (1.f / 8192.f);
  float v = q * (1.f / 8192.f) - m * m;
  float sc = g1[o] * rsqrtf(v + EPSBN);
  float sh = bt1[o] - m * sc;
  if (isq) {
    const int row = blockIdx.x * 4 + r;
    float vv = sc * h2[(size_t)row * 64 + o] + sh;
    qb[(size_t)row * 64 + o] = f2bf(vv);
    float sq = vv * vv;
    #pragma unroll
    for (int off = 32; off; off >>= 1) sq += __shfl_xor(sq, off);
    if (o == 0) qn2[row] = SCL * sq;
  } else {
    const int row = (blockIdx.x - 2048) * 4 + r;   // 0..8831
    const int src = pidx[row];
    float vv = 0.f;
    if (src >= 0) vv = sc * h2[(size_t)(NROWS + src) * 64 + o] + sh;
    kb[(size_t)row * 64 + o] = f2bf(vv);
    float sq = vv * vv;
    #pragma unroll
    for (int off = 32; off; off >>= 1) sq += __shfl_xor(sq, off);
    if (o == 0) kn2[row] = (src >= 0) ? SCL * sq : 1e30f;
  }
}

// -------- cdist: 1-pass bf16, 64-col tiles, TRIPLE buffer + counted vmcnt --------
__global__ __launch_bounds__(256, 4) void k_dist(
    const u16* __restrict__ qb, const float* __restrict__ qn2,
    const u16* __restrict__ kb, const float* __restrict__ kn2,
    const int* __restrict__ tcls, float* __restrict__ part)
{
  __shared__ u16 bs[3][4096];                       // 3 x 8 KB
  __shared__ float cls_lds[2 * (NCLS + 1) * 64];
  const int tid = threadIdx.x;
  const int w = tid >> 6, l = tid & 63;
  const int n0 = blockIdx.x * 64;
  const int g = blockIdx.y;
  const int t0 = (g * NT_PAD) / GY, t1 = ((g + 1) * NT_PAD) / GY;

  for (int i = tid; i < 2 * (NCLS + 1) * 64; i += 256) cls_lds[i] = 0.f;

  const int lh = l >> 5;
  const int rb = w >> 1, ch = w & 1;
  const int arow = n0 + 32 * rb + (l & 31);
  bf16x8 aB[4];
  #pragma unroll
  for (int j = 0; j < 4; ++j)
    aB[j] = *(const bf16x8*)(qb + (size_t)arow * 64 + j * 16 + 8 * lh);
  float qnr[16];
  #pragma unroll
  for (int g4 = 0; g4 < 4; ++g4) {
    f32x4 qv = *(const f32x4*)(qn2 + n0 + 32 * rb + 8 * g4 + 4 * lh);
    qnr[4*g4+0] = qv[0]; qnr[4*g4+1] = qv[1]; qnr[4*g4+2] = qv[2]; qnr[4*g4+3] = qv[3];
  }

  int soff[2];
  #pragma unroll
  for (int q = 0; q < 2; ++q)
    soff[q] = (16 * w + 8 * q + (l >> 3)) * 64 + ((l & 7) ^ (l >> 3)) * 8;   // u16 units

  const int colL = 32 * ch + (l & 31);
  const int c7 = colL & 7;

#define STAGE(TT, PB) do { const u16* gp_ = kb + (size_t)(TT) * 4096; \
    u16* lb_ = &bs[PB][0] + w * 1024; \
    glds16(gp_ + soff[0], lb_); \
    glds16(gp_ + soff[1], lb_ + 512); } while (0)

#define FLUSH(CC) do { \
    _Pragma("unroll") for (int r = 0; r < 16; ++r) { \
      run[r] += __shfl_xor(run[r], 1);  run[r] += __shfl_xor(run[r], 2); \
      run[r] += __shfl_xor(run[r], 4);  run[r] += __shfl_xor(run[r], 8); \
      run[r] += __shfl_xor(run[r], 16); } \
    if ((l & 31) == 0) { \
      float* cl_ = cls_lds + ch * 704 + (CC) * 64 + 32 * rb + 4 * lh; \
      _Pragma("unroll") for (int r = 0; r < 16; ++r) cl_[(r & 3) + 8 * (r >> 2)] += run[r]; } \
    _Pragma("unroll") for (int r = 0; r < 16; ++r) run[r] = 0.f; } while (0)

  STAGE(t0, 0);
  if (t0 + 1 < t1) STAGE(t0 + 1, 1);

  float run[16];
  #pragma unroll
  for (int r = 0; r < 16; ++r) run[r] = 0.f;
  int ccur = tcls[t0];
  int p = 0;

  for (int t = t0; t < t1; ++t) {
    if (t + 1 < t1) { asm volatile("s_waitcnt vmcnt(2)" ::: "memory"); }
    else            { asm volatile("s_waitcnt vmcnt(0)" ::: "memory"); }
    __builtin_amdgcn_s_barrier();
    asm volatile("" ::: "memory");

    if (t + 2 < t1) { int pb2 = p + 2; if (pb2 >= 3) pb2 -= 3; STAGE(t + 2, pb2); }

    const int c = tcls[t];
    if (c != ccur) { FLUSH(ccur); ccur = c; }
    const float kv = kn2[t * 64 + colL];

    f32x16 acc0, acc1;
    #pragma unroll
    for (int r = 0; r < 16; ++r) { acc0[r] = 0.f; acc1[r] = 0.f; }
    const char* pb_ = (const char*)&bs[p][0] + colL * 128;
    {
      bf16x8 b0_ = *(const bf16x8*)(pb_ + (((0 + lh) ^ c7) << 4));
      bf16x8 b1_ = *(const bf16x8*)(pb_ + (((2 + lh) ^ c7) << 4));
      bf16x8 b2_ = *(const bf16x8*)(pb_ + (((4 + lh) ^ c7) << 4));
      bf16x8 b3_ = *(const bf16x8*)(pb_ + (((6 + lh) ^ c7) << 4));
      acc0 = __builtin_amdgcn_mfma_f32_32x32x16_bf16(aB[0], b0_, acc0, 0, 0, 0);
      acc1 = __builtin_amdgcn_mfma_f32_32x32x16_bf16(aB[1], b1_, acc1, 0, 0, 0);
      acc0 = __builtin_amdgcn_mfma_f32_32x32x16_bf16(aB[2], b2_, acc0, 0, 0, 0);
      acc1 = __builtin_amdgcn_mfma_f32_32x32x16_bf16(aB[3], b3_, acc1, 0, 0, 0);
    }
    #pragma unroll
    for (int r = 0; r < 16; ++r) {
      float d2 = fmaf(SCL2, acc0[r] + acc1[r], qnr[r] + kv);
      d2 = fmaxf(d2, 2.0813689e-12f);
      run[r] += __builtin_amdgcn_exp2f(-__builtin_amdgcn_sqrtf(d2));
    }
    p = (p == 2) ? 0 : p + 1;
  }
  FLUSH(ccur);
  __syncthreads();

  for (int i = tid; i < (NCLS + 1) * 64; i += 256) {
    const int c = i >> 6, rr = i & 63;
    part[((size_t)g * (NCLS + 1) + c) * NROWS + n0 + rr] = cls_lds[i] + cls_lds[704 + i];
  }
#undef STAGE
#undef FLUSH
}

// ---- finalize ----
__global__ __launch_bounds__(256) void k_final(const float* __restrict__ part,
                                               float* __restrict__ out)
{
  const int n = blockIdx.x * 256 + threadIdx.x;
  float sc[NCLS];
  #pragma unroll
  for (int c = 0; c < NCLS; ++c) sc[c] = 0.f;
  for (int g = 0; g < GY; ++g) {
    #pragma unroll
    for (int c = 0; c < NCLS; ++c)
      sc[c] += part[((size_t)g * (NCLS + 1) + c) * NROWS + n];
  }
  float tot = 0.f;
  #pragma unroll
  for (int c = 0; c < NCLS; ++c) tot += sc[c];
  const float inv = 1.f / tot;
  #pragma unroll
  for (int c = 0; c < NCLS; ++c)
    out[(size_t)n * NCLS + c] = fminf(fmaxf(sc[c] * inv, 0.f), 1.f);
}

extern "C" void kernel_launch(void* const* d_in, const int* in_sizes, int n_in,
                              void* d_out, int out_size, void* d_ws, size_t ws_size,
                              hipStream_t stream) {
  const float* x   = (const float*)d_in[0];
  const float* xn  = (const float*)d_in[1];
  const int*   yn  = (const int*)d_in[2];
  const float* W0  = (const float*)d_in[3];
  const float* b0  = (const float*)d_in[4];
  const float* g0  = (const float*)d_in[5];
  const float* bt0 = (const float*)d_in[6];
  const float* W1  = (const float*)d_in[7];
  const float* b1  = (const float*)d_in[8];
  const float* g1  = (const float*)d_in[9];
  const float* bt1 = (const float*)d_in[10];
  float* out = (float*)d_out;
  float* ws  = (float*)d_ws;

  u16*   w0pp = (u16*)(ws + OFF_W0P);
  u16*   h1hp = (u16*)(ws + OFF_H1H);
  u16*   h1lp = (u16*)(ws + OFF_H1L);
  float* sumsp= ws + OFF_SUM;
  u16*   w1pp = (u16*)(ws + OFF_W1P);
  float* b1ep = ws + OFF_B1E;
  float* h2p  = ws + OFF_H2;
  int*   pidxp= (int*)(ws + OFF_PIDX);
  int*   tclsp= (int*)(ws + OFF_TCLS);
  u16*   qbp  = (u16*)(ws + OFF_QB);
  float* qn2p = ws + OFF_QN2;
  u16*   kbp  = (u16*)(ws + OFF_KB);
  float* kn2p = ws + OFF_KN2;
  float* partp= ws + OFF_PART;

  hipMemsetAsync((void*)sumsp, 0, (768 + 160) * sizeof(float), stream);
  k_prep<<<129, 256, 0, stream>>>(W0, yn, w0pp, pidxp, tclsp);
  k_layer1<<<512, 256, 0, stream>>>(x, xn, w0pp, b0, h1hp, h1lp, sumsp);
  k_foldp<<<64, 128, 0, stream>>>(W1, b1, g0, bt0, sumsp, w1pp, b1ep);
  k_layer2<<<512, 256, 0, stream>>>(h1hp, h1lp, w1pp, b1ep, h2p, sumsp);
  k_bn2<<<2048 + MPAD / 4, 256, 0, stream>>>(h2p, sumsp, g1, bt1, pidxp,
                                             qbp, qn2p, kbp, kn2p);
  k_dist<<<dim3(128, GY), 256, 0, stream>>>(qbp, qn2p, kbp, kn2p, tclsp, partp);
  k_final<<<32, 256, 0, stream>>>(partp, out);
}

// Round 11
// 140.936 us; speedup vs baseline: 4.9290x; 1.0111x over previous
//
#include <hip/hip_runtime.h>
#include <math.h>

#define EPSBN 1e-5f
#define AADD(p, v) __hip_atomic_fetch_add((p), (v), __ATOMIC_RELAXED, __HIP_MEMORY_SCOPE_AGENT)

typedef unsigned short u16;
typedef short bf16x8 __attribute__((ext_vector_type(8)));
typedef float f32x4 __attribute__((ext_vector_type(4)));
typedef float f32x16 __attribute__((ext_vector_type(16)));

constexpr int NROWS = 8192;
constexpr int NCLS = 10;
constexpr int MPAD = 8832;        // 138 tiles of 64
constexpr int NT_PAD = 138;
constexpr int GY = 8;
constexpr float SCL  = 2.0813689810056077f;   // (log2 e)^2
constexpr float SCL2 = -4.1627379620112154f;  // -2*(log2 e)^2

// workspace offsets (floats)
constexpr size_t OFF_W0P = 0;                      // u16[65536]
constexpr size_t OFF_H1H = 32768;                  // u16[16384*128] = 1048576 f
constexpr size_t OFF_H1L = OFF_H1H + 1048576;
constexpr size_t OFF_SUM = OFF_H1L + 1048576;      // 768 f (zeroed in k_prep)
constexpr size_t OFF_W1P = OFF_SUM + 768;          // u16[32768]
constexpr size_t OFF_B1E = OFF_W1P + 16384;        // 128 f
constexpr size_t OFF_H2  = OFF_B1E + 128;          // 16384*64 f
constexpr size_t OFF_PIDX = OFF_H2 + 1048576;      // int[8832]
constexpr size_t OFF_TCLS = OFF_PIDX + MPAD;       // int[144]
// overlays over h1 (dead after layer2)
constexpr size_t OFF_QB  = OFF_H1H;                // u16[8192*64]  = 262144 f
constexpr size_t OFF_KB  = OFF_QB + 262144;        // u16[8832*64]  = 282624 f
constexpr size_t OFF_QN2 = OFF_KB + 282624;        // 8192 f
constexpr size_t OFF_KN2 = OFF_QN2 + NROWS;        // 8832 f
// part over h2 (dead after bn2): 8*11*8192 = 720896 <= 1048576
constexpr size_t OFF_PART = OFF_H2;

__device__ inline u16 f2bf(float f) {
  unsigned u = __float_as_uint(f);
  unsigned r = (u + 0x7fffu + ((u >> 16) & 1u)) >> 16;
  return (u16)r;
}
__device__ inline float bf2f(u16 h) { return __uint_as_float(((unsigned)h) << 16); }

__device__ inline float tanh_fast(float x) {
  float e = __builtin_amdgcn_exp2f(x * 2.88539008f);
  return 1.f - 2.f * __builtin_amdgcn_rcpf(e + 1.f);
}

__device__ inline void glds16(const u16* g, u16* l) {
  __builtin_amdgcn_global_load_lds(
      (const __attribute__((address_space(1))) unsigned int*)g,
      (__attribute__((address_space(3))) unsigned int*)l, 16, 0, 0);
}

// ---------------- prep: W0 pack (0-127) | aux (128) | per-class scatter (129-138) --
// All sort blocks compute the identical histogram -> identical padded pstart.
// Writes are disjoint: aux writes tcls + PAD slots of pidx; block 129+c writes
// exactly the class-c index range. Kernel boundary publishes everything.
__global__ __launch_bounds__(256) void k_prep(
    const float* __restrict__ w0, const int* __restrict__ yn,
    u16* __restrict__ w0p, int* __restrict__ pidx, int* __restrict__ tcls,
    float* __restrict__ sums)
{
  const int B = blockIdx.x;
  const int tid = threadIdx.x;
  if (B < 128) {
    int idx = B * 256 + tid;
    int t = idx & 255;
    float v = w0[idx];
    u16 hi = f2bf(v);
    u16 lo = f2bf(v - bf2f(hi));
    int j = idx >> 8;
    w0p[(t >> 3) * 1024 + j * 8 + (t & 7)] = hi;
    w0p[32768 + (t >> 3) * 1024 + j * 8 + (t & 7)] = lo;
    return;
  }

  // ---- shared histogram (identical in every sort block) ----
  __shared__ int cnt[256][NCLS];
  __shared__ int counts[NCLS];
  __shared__ int pst[NCLS + 1];
  const int lane = tid & 63, wv = tid >> 6;
  #pragma unroll
  for (int c = 0; c < NCLS; ++c) cnt[tid][c] = 0;
  __syncthreads();
  for (int i = tid; i < NROWS; i += 256) cnt[tid][yn[i]]++;
  __syncthreads();
  if (tid < NCLS) {
    int s = 0;
    for (int t = 0; t < 256; ++t) s += cnt[t][tid];
    counts[tid] = s;
  }
  __syncthreads();
  if (tid == 0) {
    int run = 0;
    #pragma unroll
    for (int c = 0; c < NCLS; ++c) {
      pst[c] = run;
      run += ((counts[c] + 63) >> 6) << 6;
    }
    pst[NCLS] = run;
  }
  __syncthreads();

  if (B == 128) {
    // zero BN-stat accumulators (replaces hipMemsetAsync)
    sums[tid] = 0.f; sums[tid + 256] = 0.f; sums[tid + 512] = 0.f;
    // tcls fill
    if (tid == 0) {
      #pragma unroll
      for (int c = 0; c < NCLS; ++c) {
        int nt = (counts[c] + 63) >> 6;
        for (int tt = 0; tt < nt; ++tt) tcls[(pst[c] >> 6) + tt] = c;
      }
      for (int tt = pst[NCLS] >> 6; tt < NT_PAD; ++tt) tcls[tt] = NCLS;
    }
    // -1 into PAD slots only (disjoint from scatter writes)
    for (int i = tid; i < MPAD; i += 256) {
      bool pad;
      if (i >= pst[NCLS]) pad = true;
      else {
        int c = 0;
        while (i >= pst[c + 1]) ++c;
        pad = (i >= pst[c] + counts[c]);
      }
      if (pad) pidx[i] = -1;
    }
    return;
  }

  // ---- scatter block for class c = B - 129 ----
  const int c = B - 129;
  __shared__ int wsum[4];
  int x = cnt[tid][c];
  int inc = x;
  #pragma unroll
  for (int d = 1; d < 64; d <<= 1) { int y = __shfl_up(inc, d); if (lane >= d) inc += y; }
  if (lane == 63) wsum[wv] = inc;
  __syncthreads();
  int add = 0;
  for (int w2 = 0; w2 < 4; ++w2) if (w2 < wv) add += wsum[w2];
  int base = pst[c] + (inc - x) + add;
  for (int i = tid; i < NROWS; i += 256) {
    if (yn[i] == c) pidx[base++] = i;
  }
}

// ---------------- layer 1 (3-pass MFMA, relaxed atomic BN stats only) -----------
__global__ __launch_bounds__(256) void k_layer1(
    const float* __restrict__ x, const float* __restrict__ xn,
    const u16* __restrict__ w0p, const float* __restrict__ b0,
    u16* __restrict__ h1h, u16* __restrict__ h1l, float* __restrict__ sums)
{
  const int tid = threadIdx.x;
  const int w = tid >> 6, l = tid & 63;
  const int l15 = l & 15, l4 = l >> 4;
  const int blk = blockIdx.x;                 // 512
  const int rowHalf = w & 1, colHalf = w >> 1;
  const int r0 = blk * 32 + 16 * rowHalf;
  const int c0 = 64 * colHalf;
  const int b = (blk < 256) ? 0 : 1;
  const float* src = (blk < 256) ? (x + (size_t)blk * 32 * 256)
                                 : (xn + (size_t)(blk - 256) * 32 * 256);
  const float* xrow = src + (size_t)(16 * rowHalf + l15) * 256;

  f32x4 acc[4];
  #pragma unroll
  for (int ct = 0; ct < 4; ++ct) acc[ct] = (f32x4){0.f, 0.f, 0.f, 0.f};

  #pragma unroll
  for (int ks = 0; ks < 8; ++ks) {
    const float* xp = xrow + ks * 32 + l4 * 8;
    f32x4 a0 = *(const f32x4*)xp;
    f32x4 a1 = *(const f32x4*)(xp + 4);
    bf16x8 ah, al_;
    #pragma unroll
    for (int i = 0; i < 4; ++i) {
      u16 h = f2bf(a0[i]); ah[i] = (short)h; al_[i] = (short)f2bf(a0[i] - bf2f(h));
    }
    #pragma unroll
    for (int i = 0; i < 4; ++i) {
      u16 h = f2bf(a1[i]); ah[4 + i] = (short)h; al_[4 + i] = (short)f2bf(a1[i] - bf2f(h));
    }
    const u16* bbase = w0p + (size_t)(ks * 4 + l4) * 1024;
    #pragma unroll
    for (int ct = 0; ct < 4; ++ct) {
      const int col = c0 + 16 * ct + l15;
      bf16x8 bh = *(const bf16x8*)(bbase + col * 8);
      bf16x8 bl = *(const bf16x8*)(bbase + 32768 + col * 8);
      acc[ct] = __builtin_amdgcn_mfma_f32_16x16x32_bf16(ah, bh, acc[ct], 0, 0, 0);
      acc[ct] = __builtin_amdgcn_mfma_f32_16x16x32_bf16(ah, bl, acc[ct], 0, 0, 0);
      acc[ct] = __builtin_amdgcn_mfma_f32_16x16x32_bf16(al_, bh, acc[ct], 0, 0, 0);
    }
  }

  #pragma unroll
  for (int ct = 0; ct < 4; ++ct) {
    const int col = c0 + 16 * ct + l15;
    const float bj = b0[col];
    float s = 0.f, q = 0.f;
    #pragma unroll
    for (int r = 0; r < 4; ++r) {
      float v = tanh_fast(acc[ct][r] + bj);
      const int row = r0 + 4 * l4 + r;
      u16 hi = f2bf(v);
      h1h[(size_t)row * 128 + col] = hi;
      h1l[(size_t)row * 128 + col] = f2bf(v - bf2f(hi));
      s += v; q += v * v;
    }
    s += __shfl_xor(s, 16); s += __shfl_xor(s, 32);
    q += __shfl_xor(q, 16); q += __shfl_xor(q, 32);
    if (l < 16) {
      AADD(&sums[b * 128 + col], s);
      AADD(&sums[256 + b * 128 + col], q);
    }
  }
}

// ---- parallel fold: BN1 scale/shift from sums -> packed W1eff + eff bias ----
__global__ __launch_bounds__(128) void k_foldp(
    const float* __restrict__ w1, const float* __restrict__ b1,
    const float* __restrict__ g0, const float* __restrict__ bt0,
    const float* __restrict__ sums, u16* __restrict__ w1p, float* __restrict__ b1e)
{
  const int o = blockIdx.x;          // 64
  const int j = threadIdx.x;         // 128
  __shared__ float red[2][2];
  const float w = w1[o * 128 + j];
  #pragma unroll
  for (int b = 0; b < 2; ++b) {
    float s = sums[b * 128 + j], q = sums[256 + b * 128 + j];
    float m = s * (1.f / 8192.f);
    float v = q * (1.f / 8192.f) - m * m;
    float sc = g0[j] * rsqrtf(v + EPSBN);
    float sh = bt0[j] - m * sc;
    float wsc = w * sc;
    u16 hi = f2bf(wsc);
    u16 lo = f2bf(wsc - bf2f(hi));
    w1p[((size_t)(b * 2 + 0) * 16 + (j >> 3)) * 512 + o * 8 + (j & 7)] = hi;
    w1p[((size_t)(b * 2 + 1) * 16 + (j >> 3)) * 512 + o * 8 + (j & 7)] = lo;
    float a = w * sh;
    #pragma unroll
    for (int off = 32; off; off >>= 1) a += __shfl_xor(a, off);
    if ((j & 63) == 0) red[j >> 6][b] = a;
  }
  __syncthreads();
  if (j < 2) b1e[j * 64 + o] = b1[o] + red[0][j] + red[1][j];
}

// ---------------- layer 2 (3-pass MFMA, atomic BN stats) ----------------
__global__ __launch_bounds__(256) void k_layer2(
    const u16* __restrict__ h1h, const u16* __restrict__ h1l,
    const u16* __restrict__ w1p, const float* __restrict__ b1e,
    float* __restrict__ h2, float* __restrict__ sums)
{
  const int tid = threadIdx.x;
  const int w = tid >> 6, l = tid & 63;
  const int l15 = l & 15, l4 = l >> 4;
  const int blk = blockIdx.x;
  const int rowHalf = w & 1, colHalf = w >> 1;
  const int r0 = blk * 32 + 16 * rowHalf;
  const int c0 = 32 * colHalf;
  const int b = blk >> 8;
  const u16* arow_h = h1h + (size_t)(r0 + l15) * 128;
  const u16* arow_l = h1l + (size_t)(r0 + l15) * 128;

  f32x4 acc[2];
  acc[0] = (f32x4){0.f, 0.f, 0.f, 0.f};
  acc[1] = (f32x4){0.f, 0.f, 0.f, 0.f};

  #pragma unroll
  for (int ks = 0; ks < 4; ++ks) {
    bf16x8 ah = *(const bf16x8*)(arow_h + ks * 32 + l4 * 8);
    bf16x8 al_ = *(const bf16x8*)(arow_l + ks * 32 + l4 * 8);
    const u16* bb = w1p + ((size_t)(b * 2) * 16 + ks * 4 + l4) * 512;
    #pragma unroll
    for (int ct = 0; ct < 2; ++ct) {
      const int col = c0 + 16 * ct + l15;
      bf16x8 bh = *(const bf16x8*)(bb + col * 8);
      bf16x8 bl = *(const bf16x8*)(bb + 8192 + col * 8);
      acc[ct] = __builtin_amdgcn_mfma_f32_16x16x32_bf16(ah, bh, acc[ct], 0, 0, 0);
      acc[ct] = __builtin_amdgcn_mfma_f32_16x16x32_bf16(ah, bl, acc[ct], 0, 0, 0);
      acc[ct] = __builtin_amdgcn_mfma_f32_16x16x32_bf16(al_, bh, acc[ct], 0, 0, 0);
    }
  }

  #pragma unroll
  for (int ct = 0; ct < 2; ++ct) {
    const int col = c0 + 16 * ct + l15;
    const float bj = b1e[b * 64 + col];
    float s = 0.f, q = 0.f;
    #pragma unroll
    for (int r = 0; r < 4; ++r) {
      float v = tanh_fast(acc[ct][r] + bj);
      const int row = r0 + 4 * l4 + r;
      h2[(size_t)row * 64 + col] = v;
      s += v; q += v * v;
    }
    s += __shfl_xor(s, 16); s += __shfl_xor(s, 32);
    q += __shfl_xor(q, 16); q += __shfl_xor(q, 32);
    if (l < 16) {
      AADD(&sums[512 + b * 64 + col], s);
      AADD(&sums[640 + b * 64 + col], q);
    }
  }
}

// ---------------- BN2 + single-bf16 round (q + permuted/padded k) ----------------
__global__ __launch_bounds__(256) void k_bn2(
    const float* __restrict__ h2, const float* __restrict__ sums,
    const float* __restrict__ g1, const float* __restrict__ bt1,
    const int* __restrict__ pidx,
    u16* __restrict__ qb, float* __restrict__ qn2,
    u16* __restrict__ kb, float* __restrict__ kn2)
{
  const int tid = threadIdx.x;
  const int r = tid >> 6, o = tid & 63;
  const bool isq = (blockIdx.x < 2048);
  const int b = isq ? 0 : 1;
  float s = sums[512 + b * 64 + o], q = sums[640 + b * 64 + o];
  float m = s * (1.f / 8192.f);
  float v = q * (1.f / 8192.f) - m * m;
  float sc = g1[o] * rsqrtf(v + EPSBN);
  float sh = bt1[o] - m * sc;
  if (isq) {
    const int row = blockIdx.x * 4 + r;
    float vv = sc * h2[(size_t)row * 64 + o] + sh;
    qb[(size_t)row * 64 + o] = f2bf(vv);
    float sq = vv * vv;
    #pragma unroll
    for (int off = 32; off; off >>= 1) sq += __shfl_xor(sq, off);
    if (o == 0) qn2[row] = SCL * sq;
  } else {
    const int row = (blockIdx.x - 2048) * 4 + r;   // 0..8831
    const int src = pidx[row];
    float vv = 0.f;
    if (src >= 0) vv = sc * h2[(size_t)(NROWS + src) * 64 + o] + sh;
    kb[(size_t)row * 64 + o] = f2bf(vv);
    float sq = vv * vv;
    #pragma unroll
    for (int off = 32; off; off >>= 1) sq += __shfl_xor(sq, off);
    if (o == 0) kn2[row] = (src >= 0) ? SCL * sq : 1e30f;
  }
}

// -------- cdist: 1-pass bf16, 64-col tiles, TRIPLE buffer + counted vmcnt --------
__global__ __launch_bounds__(256, 4) void k_dist(
    const u16* __restrict__ qb, const float* __restrict__ qn2,
    const u16* __restrict__ kb, const float* __restrict__ kn2,
    const int* __restrict__ tcls, float* __restrict__ part)
{
  __shared__ u16 bs[3][4096];                       // 3 x 8 KB
  __shared__ float cls_lds[2 * (NCLS + 1) * 64];
  const int tid = threadIdx.x;
  const int w = tid >> 6, l = tid & 63;
  const int n0 = blockIdx.x * 64;
  const int g = blockIdx.y;
  const int t0 = (g * NT_PAD) / GY, t1 = ((g + 1) * NT_PAD) / GY;

  for (int i = tid; i < 2 * (NCLS + 1) * 64; i += 256) cls_lds[i] = 0.f;

  const int lh = l >> 5;
  const int rb = w >> 1, ch = w & 1;
  const int arow = n0 + 32 * rb + (l & 31);
  bf16x8 aB[4];
  #pragma unroll
  for (int j = 0; j < 4; ++j)
    aB[j] = *(const bf16x8*)(qb + (size_t)arow * 64 + j * 16 + 8 * lh);
  float qnr[16];
  #pragma unroll
  for (int g4 = 0; g4 < 4; ++g4) {
    f32x4 qv = *(const f32x4*)(qn2 + n0 + 32 * rb + 8 * g4 + 4 * lh);
    qnr[4*g4+0] = qv[0]; qnr[4*g4+1] = qv[1]; qnr[4*g4+2] = qv[2]; qnr[4*g4+3] = qv[3];
  }

  int soff[2];
  #pragma unroll
  for (int q = 0; q < 2; ++q)
    soff[q] = (16 * w + 8 * q + (l >> 3)) * 64 + ((l & 7) ^ (l >> 3)) * 8;   // u16 units

  const int colL = 32 * ch + (l & 31);
  const int c7 = colL & 7;

#define STAGE(TT, PB) do { const u16* gp_ = kb + (size_t)(TT) * 4096; \
    u16* lb_ = &bs[PB][0] + w * 1024; \
    glds16(gp_ + soff[0], lb_); \
    glds16(gp_ + soff[1], lb_ + 512); } while (0)

#define FLUSH(CC) do { \
    _Pragma("unroll") for (int r = 0; r < 16; ++r) { \
      run[r] += __shfl_xor(run[r], 1);  run[r] += __shfl_xor(run[r], 2); \
      run[r] += __shfl_xor(run[r], 4);  run[r] += __shfl_xor(run[r], 8); \
      run[r] += __shfl_xor(run[r], 16); } \
    if ((l & 31) == 0) { \
      float* cl_ = cls_lds + ch * 704 + (CC) * 64 + 32 * rb + 4 * lh; \
      _Pragma("unroll") for (int r = 0; r < 16; ++r) cl_[(r & 3) + 8 * (r >> 2)] += run[r]; } \
    _Pragma("unroll") for (int r = 0; r < 16; ++r) run[r] = 0.f; } while (0)

  STAGE(t0, 0);
  if (t0 + 1 < t1) STAGE(t0 + 1, 1);

  float run[16];
  #pragma unroll
  for (int r = 0; r < 16; ++r) run[r] = 0.f;
  int ccur = tcls[t0];
  int p = 0;

  for (int t = t0; t < t1; ++t) {
    if (t + 1 < t1) { asm volatile("s_waitcnt vmcnt(2)" ::: "memory"); }
    else            { asm volatile("s_waitcnt vmcnt(0)" ::: "memory"); }
    __builtin_amdgcn_s_barrier();
    asm volatile("" ::: "memory");

    if (t + 2 < t1) { int pb2 = p + 2; if (pb2 >= 3) pb2 -= 3; STAGE(t + 2, pb2); }

    const int c = tcls[t];
    if (c != ccur) { FLUSH(ccur); ccur = c; }
    const float kv = kn2[t * 64 + colL];

    f32x16 acc0, acc1;
    #pragma unroll
    for (int r = 0; r < 16; ++r) { acc0[r] = 0.f; acc1[r] = 0.f; }
    const char* pb_ = (const char*)&bs[p][0] + colL * 128;
    {
      bf16x8 b0_ = *(const bf16x8*)(pb_ + (((0 + lh) ^ c7) << 4));
      bf16x8 b1_ = *(const bf16x8*)(pb_ + (((2 + lh) ^ c7) << 4));
      bf16x8 b2_ = *(const bf16x8*)(pb_ + (((4 + lh) ^ c7) << 4));
      bf16x8 b3_ = *(const bf16x8*)(pb_ + (((6 + lh) ^ c7) << 4));
      acc0 = __builtin_amdgcn_mfma_f32_32x32x16_bf16(aB[0], b0_, acc0, 0, 0, 0);
      acc1 = __builtin_amdgcn_mfma_f32_32x32x16_bf16(aB[1], b1_, acc1, 0, 0, 0);
      acc0 = __builtin_amdgcn_mfma_f32_32x32x16_bf16(aB[2], b2_, acc0, 0, 0, 0);
      acc1 = __builtin_amdgcn_mfma_f32_32x32x16_bf16(aB[3], b3_, acc1, 0, 0, 0);
    }
    #pragma unroll
    for (int r = 0; r < 16; ++r) {
      float d2 = fmaf(SCL2, acc0[r] + acc1[r], qnr[r] + kv);
      d2 = fmaxf(d2, 2.0813689e-12f);
      run[r] += __builtin_amdgcn_exp2f(-__builtin_amdgcn_sqrtf(d2));
    }
    p = (p == 2) ? 0 : p + 1;
  }
  FLUSH(ccur);
  __syncthreads();

  for (int i = tid; i < (NCLS + 1) * 64; i += 256) {
    const int c = i >> 6, rr = i & 63;
    part[((size_t)g * (NCLS + 1) + c) * NROWS + n0 + rr] = cls_lds[i] + cls_lds[704 + i];
  }
#undef STAGE
#undef FLUSH
}

// ---- finalize ----
__global__ __launch_bounds__(256) void k_final(const float* __restrict__ part,
                                               float* __restrict__ out)
{
  const int n = blockIdx.x * 256 + threadIdx.x;
  float sc[NCLS];
  #pragma unroll
  for (int c = 0; c < NCLS; ++c) sc[c] = 0.f;
  for (int g = 0; g < GY; ++g) {
    #pragma unroll
    for (int c = 0; c < NCLS; ++c)
      sc[c] += part[((size_t)g * (NCLS + 1) + c) * NROWS + n];
  }
  float tot = 0.f;
  #pragma unroll
  for (int c = 0; c < NCLS; ++c) tot += sc[c];
  const float inv = 1.f / tot;
  #pragma unroll
  for (int c = 0; c < NCLS; ++c)
    out[(size_t)n * NCLS + c] = fminf(fmaxf(sc[c] * inv, 0.f), 1.f);
}

extern "C" void kernel_launch(void* const* d_in, const int* in_sizes, int n_in,
                              void* d_out, int out_size, void* d_ws, size_t ws_size,
                              hipStream_t stream) {
  const float* x   = (const float*)d_in[0];
  const float* xn  = (const float*)d_in[1];
  const int*   yn  = (const int*)d_in[2];
  const float* W0  = (const float*)d_in[3];
  const float* b0  = (const float*)d_in[4];
  const float* g0  = (const float*)d_in[5];
  const float* bt0 = (const float*)d_in[6];
  const float* W1  = (const float*)d_in[7];
  const float* b1  = (const float*)d_in[8];
  const float* g1  = (const float*)d_in[9];
  const float* bt1 = (const float*)d_in[10];
  float* out = (float*)d_out;
  float* ws  = (float*)d_ws;

  u16*   w0pp = (u16*)(ws + OFF_W0P);
  u16*   h1hp = (u16*)(ws + OFF_H1H);
  u16*   h1lp = (u16*)(ws + OFF_H1L);
  float* sumsp= ws + OFF_SUM;
  u16*   w1pp = (u16*)(ws + OFF_W1P);
  float* b1ep = ws + OFF_B1E;
  float* h2p  = ws + OFF_H2;
  int*   pidxp= (int*)(ws + OFF_PIDX);
  int*   tclsp= (int*)(ws + OFF_TCLS);
  u16*   qbp  = (u16*)(ws + OFF_QB);
  float* qn2p = ws + OFF_QN2;
  u16*   kbp  = (u16*)(ws + OFF_KB);
  float* kn2p = ws + OFF_KN2;
  float* partp= ws + OFF_PART;

  k_prep<<<139, 256, 0, stream>>>(W0, yn, w0pp, pidxp, tclsp, sumsp);
  k_layer1<<<512, 256, 0, stream>>>(x, xn, w0pp, b0, h1hp, h1lp, sumsp);
  k_foldp<<<64, 128, 0, stream>>>(W1, b1, g0, bt0, sumsp, w1pp, b1ep);
  k_layer2<<<512, 256, 0, stream>>>(h1hp, h1lp, w1pp, b1ep, h2p, sumsp);
  k_bn2<<<2048 + MPAD / 4, 256, 0, stream>>>(h2p, sumsp, g1, bt1, pidxp,
                                             qbp, qn2p, kbp, kn2p);
  k_dist<<<dim3(128, GY), 256, 0, stream>>>(qbp, qn2p, kbp, kn2p, tclsp, partp);
  k_final<<<32, 256, 0, stream>>>(partp, out);
}